// Round 4
// baseline (13833.968 us; speedup 1.0000x reference)
//
#include <hip/hip_runtime.h>
#include <hip/hip_bf16.h>

#define BB 8
#define NN 8192
#define KK 6
#define DD 256
#define LL 5
#define NE (BB*NN*KK)       // 393216
#define INV6 (1.0f/6.000001f)

// ---------------- CSR build (all batches; off layout: b*(NN+1) + j) ----------------
__global__ void k_count(const int* __restrict__ knn, int* __restrict__ off){
  int e = blockIdx.x*256 + threadIdx.x;
  if(e >= NE) return;
  int b = e / (NN*KK);
  int j = knn[e];
  atomicAdd(&off[b*(NN+1) + 1 + j], 1);
}

// one block per batch; inclusive scan of its (NN+1)-segment
__global__ __launch_bounds__(1024) void k_scan(int* __restrict__ offAll){
  __shared__ int lds[1024];
  __shared__ int carry_s;
  int* off = offAll + blockIdx.x*(NN+1);
  const int len = NN+1;
  int t = threadIdx.x;
  if(t==0) carry_s = 0;
  __syncthreads();
  for(int base=0; base<len; base+=1024){
    int x = (base+t < len) ? off[base+t] : 0;
    lds[t] = x; __syncthreads();
    for(int s=1; s<1024; s<<=1){
      int v = (t>=s) ? lds[t-s] : 0;
      __syncthreads();
      lds[t] += v;
      __syncthreads();
    }
    int incl = lds[t];
    int carry = carry_s;
    __syncthreads();
    if(base+t < len) off[base+t] = incl + carry;
    if(t==1023) carry_s = carry + incl;
    __syncthreads();
  }
}

__global__ void k_fill(const int* __restrict__ knn, int* __restrict__ cursor, int* __restrict__ srcE){
  int e = blockIdx.x*256 + threadIdx.x;
  if(e >= NE) return;
  int b = e / (NN*KK);
  int n = (e % (NN*KK)) / KK;
  int j = knn[e];
  int pos = atomicAdd(&cursor[b*(NN+1) + j], 1);
  srcE[(long)b*NN*KK + pos] = n;
}

// ---------------- embed (one batch) ----------------
__global__ void k_embed(const float* __restrict__ x, const float* __restrict__ ew,
                        const float* __restrict__ eb, float* __restrict__ h){
  int g = blockIdx.x; int d = threadIdx.x;
  float x0 = x[g*3+0], x1 = x[g*3+1], x2 = x[g*3+2];
  h[(long)g*DD + d] = x0*ew[0*DD+d] + x1*ew[1*DD+d] + x2*ew[2*DD+d] + eb[d];
}

// ---------------- layernorm fp32 -> fp32 ----------------
__global__ __launch_bounds__(256) void k_ln(const float* __restrict__ h, const float* __restrict__ g,
                     const float* __restrict__ bia, float* __restrict__ out){
  int row = blockIdx.x*4 + (threadIdx.x >> 6);
  int lane = threadIdx.x & 63;
  const float4 x = *(const float4*)(h + (long)row*DD + lane*4);
  float s  = x.x + x.y + x.z + x.w;
  float s2 = x.x*x.x + x.y*x.y + x.z*x.z + x.w*x.w;
  for(int o=1;o<64;o<<=1){ s += __shfl_xor(s,o); s2 += __shfl_xor(s2,o); }
  float m = s*(1.0f/256.0f);
  float var = s2*(1.0f/256.0f) - m*m;
  float r = rsqrtf(var + 1e-5f);
  const float4 gu = *(const float4*)(g + lane*4);
  const float4 bu = *(const float4*)(bia + lane*4);
  float4 o4;
  o4.x = (x.x-m)*r*gu.x + bu.x;
  o4.y = (x.y-m)*r*gu.y + bu.y;
  o4.z = (x.z-m)*r*gu.z + bu.z;
  o4.w = (x.w-m)*r*gu.w + bu.w;
  *(float4*)(out + (long)row*DD + lane*4) = o4;
}

#define TS 64
#define KS 16

// A: [M x 256] fp32. W: [256 x Ncols] fp32. rowscale (nullable) scales A rows.
// accOut!=null: accOut[row,col] += res + bias (Ncols==256 path).
// else: fp32 section outs out0/1/2 (sec=col/256), relu+1e-6 per reluMask bit.
__global__ __launch_bounds__(256) void k_gemm(
    const float* __restrict__ A, const float* __restrict__ rowscale,
    const float* __restrict__ W, const float* __restrict__ bias,
    float* __restrict__ out0, float* __restrict__ out1, float* __restrict__ out2,
    float* __restrict__ accOut, int Ncols, int reluMask)
{
  __shared__ __align__(16) float As[KS][TS+4];
  __shared__ __align__(16) float Bs[KS][TS+4];
  const int rowTile = blockIdx.x * TS;
  const int colTile = blockIdx.y * TS;
  const int t  = threadIdx.x;
  const int tx = t & 15, ty = t >> 4;
  const int ar = t & 63, ak4 = (t >> 6) * 4;
  const int bk = t >> 4, bc4 = (t & 15) * 4;
  const float scale = rowscale ? rowscale[rowTile + ar] : 1.0f;
  const float* Arow = A + (long)(rowTile + ar) * 256;
  float acc[4][4];
  #pragma unroll
  for(int i=0;i<4;i++)
    #pragma unroll
    for(int j=0;j<4;j++) acc[i][j] = 0.f;

  for(int k0=0; k0<256; k0+=KS){
    float4 a4 = *(const float4*)(Arow + k0 + ak4);
    float4 w4 = *(const float4*)(W + (long)(k0+bk)*Ncols + colTile + bc4);
    __syncthreads();
    As[ak4+0][ar] = a4.x*scale; As[ak4+1][ar] = a4.y*scale;
    As[ak4+2][ar] = a4.z*scale; As[ak4+3][ar] = a4.w*scale;
    *(float4*)&Bs[bk][bc4] = w4;
    __syncthreads();
    #pragma unroll
    for(int kk=0; kk<KS; kk++){
      float4 av = *(const float4*)&As[kk][ty*4];
      float4 bv = *(const float4*)&Bs[kk][tx*4];
      acc[0][0] += av.x*bv.x; acc[0][1] += av.x*bv.y; acc[0][2] += av.x*bv.z; acc[0][3] += av.x*bv.w;
      acc[1][0] += av.y*bv.x; acc[1][1] += av.y*bv.y; acc[1][2] += av.y*bv.z; acc[1][3] += av.y*bv.w;
      acc[2][0] += av.z*bv.x; acc[2][1] += av.z*bv.y; acc[2][2] += av.z*bv.z; acc[2][3] += av.z*bv.w;
      acc[3][0] += av.w*bv.x; acc[3][1] += av.w*bv.y; acc[3][2] += av.w*bv.z; acc[3][3] += av.w*bv.w;
    }
  }
  float bv4[4];
  #pragma unroll
  for(int j=0;j<4;j++) bv4[j] = bias ? bias[colTile + tx*4 + j] : 0.f;
  if(accOut){
    #pragma unroll
    for(int i=0;i<4;i++){
      float* op = accOut + (long)(rowTile + ty*4 + i)*256 + colTile + tx*4;
      float4 o4 = *(float4*)op;
      o4.x += acc[i][0] + bv4[0];
      o4.y += acc[i][1] + bv4[1];
      o4.z += acc[i][2] + bv4[2];
      o4.w += acc[i][3] + bv4[3];
      *(float4*)op = o4;
    }
  } else {
    int sec = colTile >> 8;
    float* o = (sec==0) ? out0 : ((sec==1) ? out1 : out2);
    int csec = colTile & 255;
    bool relu = (reluMask >> sec) & 1;
    #pragma unroll
    for(int i=0;i<4;i++){
      float* op = o + (long)(rowTile + ty*4 + i)*256 + csec + tx*4;
      float4 s4;
      s4.x = acc[i][0] + bv4[0]; s4.y = acc[i][1] + bv4[1];
      s4.z = acc[i][2] + bv4[2]; s4.w = acc[i][3] + bv4[3];
      if(relu){
        s4.x = fmaxf(s4.x,0.f)+1e-6f; s4.y = fmaxf(s4.y,0.f)+1e-6f;
        s4.z = fmaxf(s4.z,0.f)+1e-6f; s4.w = fmaxf(s4.w,0.f)+1e-6f;
      }
      *(float4*)op = s4;
    }
  }
}

// ---------------- spmm gather, one batch ----------------
__global__ __launch_bounds__(256) void k_spmm1(const float* __restrict__ in,
                       const int* __restrict__ off, const int* __restrict__ srcE,
                       float* __restrict__ outp){
  int g = blockIdx.x; int d = threadIdx.x;
  int s0 = off[g], s1 = off[g+1];
  float a = 0.f;
  for(int e=s0; e<s1; e++){
    int n = srcE[e];
    a += in[(long)n*DD + d];
  }
  outp[(long)g*DD + d] = a * INV6;
}

// ---------------- rowwise dot rs = q . k3 ----------------
__global__ __launch_bounds__(256) void k_rowdot(const float* __restrict__ qb, const float* __restrict__ kb,
                         float* __restrict__ rs){
  int row = blockIdx.x*4 + (threadIdx.x >> 6);
  int lane = threadIdx.x & 63;
  const float4 a = *(const float4*)(qb + (long)row*DD + lane*4);
  const float4 c = *(const float4*)(kb + (long)row*DD + lane*4);
  float s = a.x*c.x + a.y*c.y + a.z*c.z + a.w*c.w;
  for(int o=1;o<64;o<<=1) s += __shfl_xor(s,o);
  if(lane==0) rs[row] = s;
}

// ---------------- z = 1/(q . ksum + 1e-6) ----------------
__global__ __launch_bounds__(256) void k_zcalc(const float* __restrict__ qb, const float* __restrict__ ksum,
                        float* __restrict__ rs){
  int row = blockIdx.x*4 + (threadIdx.x >> 6);
  int lane = threadIdx.x & 63;
  const float4 a = *(const float4*)(qb + (long)row*DD + lane*4);
  const float4 c = *(const float4*)(ksum + lane*4);
  float s = a.x*c.x + a.y*c.y + a.z*c.z + a.w*c.w;
  for(int o=1;o<64;o<<=1) s += __shfl_xor(s,o);
  if(lane==0) rs[row] = 1.0f / (s + 1e-6f);
}

// ---------------- ksum[d] = sum_n k[n,d]  (one batch, 16 chunks) ----------------
__global__ __launch_bounds__(256) void k_ksum(const float* __restrict__ kb, float* __restrict__ ksum){
  int c = blockIdx.x, d = threadIdx.x;
  const float* p = kb + ((long)c*512) * DD + d;
  float s = 0.f;
  for(int i=0;i<512;i++) s += p[(long)i*DD];
  atomicAdd(&ksum[d], s);
}

// ---------------- kv[d,e] = sum_n k[n,d] v[n,e] (one batch, split-K atomic) ----------------
__global__ __launch_bounds__(256) void k_kvgemm(const float* __restrict__ kp, const float* __restrict__ vp,
                         float* __restrict__ kv){
  __shared__ __align__(16) float Ks[16][68];
  __shared__ __align__(16) float Vs[16][68];
  int dT = blockIdx.x*64, eT = blockIdx.y*64;
  int sp = blockIdx.z;
  int t = threadIdx.x;
  int tx = t & 15, ty = t >> 4;
  int sk = t >> 4, sc4 = (t & 15) * 4;
  float acc[4][4];
  #pragma unroll
  for(int i=0;i<4;i++)
    #pragma unroll
    for(int j=0;j<4;j++) acc[i][j] = 0.f;
  int n0 = sp * 1024;
  for(int nn=n0; nn<n0+1024; nn+=16){
    float4 k4 = *(const float4*)(kp + (long)(nn+sk)*DD + dT + sc4);
    float4 v4 = *(const float4*)(vp + (long)(nn+sk)*DD + eT + sc4);
    __syncthreads();
    *(float4*)&Ks[sk][sc4] = k4;
    *(float4*)&Vs[sk][sc4] = v4;
    __syncthreads();
    #pragma unroll
    for(int kk=0; kk<16; kk++){
      float4 av = *(const float4*)&Ks[kk][ty*4];
      float4 bv = *(const float4*)&Vs[kk][tx*4];
      acc[0][0] += av.x*bv.x; acc[0][1] += av.x*bv.y; acc[0][2] += av.x*bv.z; acc[0][3] += av.x*bv.w;
      acc[1][0] += av.y*bv.x; acc[1][1] += av.y*bv.y; acc[1][2] += av.y*bv.z; acc[1][3] += av.y*bv.w;
      acc[2][0] += av.z*bv.x; acc[2][1] += av.z*bv.y; acc[2][2] += av.z*bv.z; acc[2][3] += av.z*bv.w;
      acc[3][0] += av.w*bv.x; acc[3][1] += av.w*bv.y; acc[3][2] += av.w*bv.z; acc[3][3] += av.w*bv.w;
    }
  }
  #pragma unroll
  for(int i=0;i<4;i++)
    #pragma unroll
    for(int j=0;j<4;j++)
      atomicAdd(&kv[(long)(dT+ty*4+i)*256 + eT+tx*4+j], acc[i][j]);
}

// ---------------- head (one batch) ----------------
__global__ __launch_bounds__(256) void k_head(const float* __restrict__ h, const float* __restrict__ hw,
                       const float* __restrict__ hb, float* __restrict__ out){
  int row = blockIdx.x*4 + (threadIdx.x >> 6);
  int lane = threadIdx.x & 63;
  const float4 x = *(const float4*)(h + (long)row*DD + lane*4);
  int d0 = lane*4;
  float a0 = x.x*hw[(d0+0)*3+0] + x.y*hw[(d0+1)*3+0] + x.z*hw[(d0+2)*3+0] + x.w*hw[(d0+3)*3+0];
  float a1 = x.x*hw[(d0+0)*3+1] + x.y*hw[(d0+1)*3+1] + x.z*hw[(d0+2)*3+1] + x.w*hw[(d0+3)*3+1];
  float a2 = x.x*hw[(d0+0)*3+2] + x.y*hw[(d0+1)*3+2] + x.z*hw[(d0+2)*3+2] + x.w*hw[(d0+3)*3+2];
  for(int o=1;o<64;o<<=1){
    a0 += __shfl_xor(a0,o); a1 += __shfl_xor(a1,o); a2 += __shfl_xor(a2,o);
  }
  if(lane==0){
    out[row*3+0] = a0 + hb[0];
    out[row*3+1] = a1 + hb[1];
    out[row*3+2] = a2 + hb[2];
  }
}

extern "C" void kernel_launch(void* const* d_in, const int* in_sizes, int n_in,
                              void* d_out, int out_size, void* d_ws, size_t ws_size,
                              hipStream_t stream)
{
  const float* x        = (const float*)d_in[0];
  const int*   knn      = (const int*)d_in[1];
  const float* emb_w    = (const float*)d_in[2];
  const float* emb_b    = (const float*)d_in[3];
  const float* norm_g   = (const float*)d_in[4];
  const float* norm_b   = (const float*)d_in[5];
  const float* grf_qkv  = (const float*)d_in[6];
  const float* grf_outw = (const float*)d_in[7];
  const float* grf_outb = (const float*)d_in[8];
  const float* attn_qkv = (const float*)d_in[9];
  const float* attn_outw= (const float*)d_in[10];
  const float* attn_outb= (const float*)d_in[11];
  const float* head_w   = (const float*)d_in[12];
  const float* head_b   = (const float*)d_in[13];
  float* out = (float*)d_out;

  // ---- workspace (~43 MiB total), all fp32 ----
  char* w = (char*)d_ws;
  const long PLF = (long)NN * DD * 4;   // 8 MiB fp32 plane (per batch)
  float* h   = (float*)w;               w += PLF;
  float* A   = (float*)w;               w += PLF;   // ln out / hop scratch
  float* Q   = (float*)w;               w += PLF;
  float* Bp  = (float*)w;               w += PLF;   // k
  float* Cp  = (float*)w;               w += PLF;   // v
  float* kv  = (float*)w;               w += (long)DD*DD*4;   // 256 KiB
  float* w2  = (float*)w;               w += (long)DD*DD*4;   // 256 KiB
  float* ksum= (float*)w;               w += DD*4;
  float* rs  = (float*)w;               w += (long)NN*4;
  int* off   = (int*)w;                 w += (long)BB*(NN+1)*4;
  int* cursor= (int*)w;                 w += (long)BB*(NN+1)*4;
  int* srcE  = (int*)w;                 w += (long)NE*4;

  // ---- CSR build for all batches ----
  hipMemsetAsync(off, 0, (long)BB*(NN+1)*sizeof(int), stream);
  k_count<<<dim3((NE+255)/256), 256, 0, stream>>>(knn, off);
  k_scan<<<dim3(BB), 1024, 0, stream>>>(off);
  hipMemcpyAsync(cursor, off, (long)BB*(NN+1)*sizeof(int), hipMemcpyDeviceToDevice, stream);
  k_fill<<<dim3((NE+255)/256), 256, 0, stream>>>(knn, cursor, srcE);

  for(int b=0; b<BB; b++){
    const int* off_b  = off  + (long)b*(NN+1);
    const int* srcE_b = srcE + (long)b*NN*KK;

    k_embed<<<dim3(NN), 256, 0, stream>>>(x + (long)b*NN*3, emb_w, emb_b, h);

    for(int i=0; i<LL; i++){
      // ===== GRF sublayer =====
      k_ln<<<dim3(NN/4), 256, 0, stream>>>(h, norm_g + (2*i)*DD, norm_b + (2*i)*DD, A);
      k_gemm<<<dim3(NN/TS, 768/TS), 256, 0, stream>>>(
          A, nullptr, grf_qkv + (long)i*DD*768, nullptr, Q, Bp, Cp, nullptr, 768, 0);
      // k hops: B->A->B->A (k3 in A)
      k_spmm1<<<dim3(NN), 256, 0, stream>>>(Bp, off_b, srcE_b, A);
      k_spmm1<<<dim3(NN), 256, 0, stream>>>(A,  off_b, srcE_b, Bp);
      k_spmm1<<<dim3(NN), 256, 0, stream>>>(Bp, off_b, srcE_b, A);
      k_rowdot<<<dim3(NN/4), 256, 0, stream>>>(Q, A, rs);
      // v hops: C->A->C->A (v3 in A; k3 dead after rowdot)
      k_spmm1<<<dim3(NN), 256, 0, stream>>>(Cp, off_b, srcE_b, A);
      k_spmm1<<<dim3(NN), 256, 0, stream>>>(A,  off_b, srcE_b, Cp);
      k_spmm1<<<dim3(NN), 256, 0, stream>>>(Cp, off_b, srcE_b, A);
      k_gemm<<<dim3(NN/TS, 256/TS), 256, 0, stream>>>(
          A, rs, grf_outw + (long)i*DD*DD, grf_outb + (long)i*DD,
          nullptr, nullptr, nullptr, h, 256, 0);

      // ===== linear attention sublayer =====
      k_ln<<<dim3(NN/4), 256, 0, stream>>>(h, norm_g + (2*i+1)*DD, norm_b + (2*i+1)*DD, A);
      k_gemm<<<dim3(NN/TS, 768/TS), 256, 0, stream>>>(
          A, nullptr, attn_qkv + (long)i*DD*768, nullptr, Q, Bp, Cp, nullptr, 768, 3);
      hipMemsetAsync(kv, 0, (long)DD*DD*sizeof(float), stream);
      hipMemsetAsync(ksum, 0, DD*sizeof(float), stream);
      k_ksum<<<dim3(16), 256, 0, stream>>>(Bp, ksum);
      k_kvgemm<<<dim3(4,4,8), 256, 0, stream>>>(Bp, Cp, kv);
      // w2 = kv @ out_w
      k_gemm<<<dim3(4, 4), 256, 0, stream>>>(
          kv, nullptr, attn_outw + (long)i*DD*DD, nullptr,
          w2, nullptr, nullptr, nullptr, 256, 0);
      k_zcalc<<<dim3(NN/4), 256, 0, stream>>>(Q, ksum, rs);
      k_gemm<<<dim3(NN/TS, 256/TS), 256, 0, stream>>>(
          Q, rs, w2, attn_outb + (long)i*DD,
          nullptr, nullptr, nullptr, h, 256, 0);
    }

    k_head<<<dim3(NN/4), 256, 0, stream>>>(h, head_w, head_b, out + (long)b*NN*3);
  }
}

// Round 6
// 6611.526 us; speedup vs baseline: 2.0924x; 2.0924x over previous
//
#include <hip/hip_runtime.h>
#include <hip/hip_bf16.h>

#define BB 8
#define NN 8192
#define KK 6
#define DD 256
#define LL 5
#define NE (BB*NN*KK)       // 393216
#define PLANE (NN*DD)       // 2097152 elems per batch
#define INV6 (1.0f/6.000001f)

typedef unsigned short u16;
typedef __attribute__((ext_vector_type(8))) short bf8;     // 8 bf16 (4 VGPRs)
typedef __attribute__((ext_vector_type(8))) unsigned short us8;
typedef __attribute__((ext_vector_type(4))) float f32x4;

__device__ __forceinline__ float b2f(u16 u){
  union { unsigned int i; float f; } c; c.i = ((unsigned int)u) << 16; return c.f;
}
__device__ __forceinline__ u16 f2b(float f){
  union { float f; unsigned int i; } c; c.f = f;
  unsigned int x = c.i;
  x += 0x7fffu + ((x >> 16) & 1u);
  return (u16)(x >> 16);
}

// ---------------- CSR build (all batches; off layout: b*(NN+1) + j) ----------------
__global__ void k_count(const int* __restrict__ knn, int* __restrict__ off){
  int e = blockIdx.x*256 + threadIdx.x;
  if(e >= NE) return;
  int b = e / (NN*KK);
  int j = knn[e];
  atomicAdd(&off[b*(NN+1) + 1 + j], 1);
}

__global__ __launch_bounds__(1024) void k_scan(int* __restrict__ offAll){
  __shared__ int lds[1024];
  __shared__ int carry_s;
  int* off = offAll + blockIdx.x*(NN+1);
  const int len = NN+1;
  int t = threadIdx.x;
  if(t==0) carry_s = 0;
  __syncthreads();
  for(int base=0; base<len; base+=1024){
    int x = (base+t < len) ? off[base+t] : 0;
    lds[t] = x; __syncthreads();
    for(int s=1; s<1024; s<<=1){
      int v = (t>=s) ? lds[t-s] : 0;
      __syncthreads();
      lds[t] += v;
      __syncthreads();
    }
    int incl = lds[t];
    int carry = carry_s;
    __syncthreads();
    if(base+t < len) off[base+t] = incl + carry;
    if(t==1023) carry_s = carry + incl;
    __syncthreads();
  }
}

__global__ void k_fill(const int* __restrict__ knn, int* __restrict__ cursor, int* __restrict__ srcE){
  int e = blockIdx.x*256 + threadIdx.x;
  if(e >= NE) return;
  int b = e / (NN*KK);
  int n = (e % (NN*KK)) / KK;
  int j = knn[e];
  int pos = atomicAdd(&cursor[b*(NN+1) + j], 1);
  srcE[(long)b*NN*KK + pos] = n;
}

// ---- weight prep: W fp32 [L][256][N] -> Wt hi/lo bf16 [L][2][N][256] ----
__global__ __launch_bounds__(256) void k_prepw(const float* __restrict__ W, u16* __restrict__ Wt, int N){
  int n = blockIdx.x, l = blockIdx.y, k = threadIdx.x;
  float x = W[((long)l*256 + k)*N + n];
  u16 h = f2b(x);
  Wt[(((long)l*2 + 0)*N + n)*256 + k] = h;
  Wt[(((long)l*2 + 1)*N + n)*256 + k] = f2b(x - b2f(h));
}

// ---------------- embed ----------------
__global__ __launch_bounds__(256) void k_embed(const float* __restrict__ x, const float* __restrict__ ew,
                        const float* __restrict__ eb, float* __restrict__ h){
  int g = blockIdx.x, z = blockIdx.y, d = threadIdx.x;
  const float* xp = x + ((long)z*NN + g)*3;
  h[(long)z*PLANE + (long)g*DD + d] = xp[0]*ew[0*DD+d] + xp[1]*ew[1*DD+d] + xp[2]*ew[2*DD+d] + eb[d];
}

// ---------------- layernorm fp32 -> fp32 ----------------
__global__ __launch_bounds__(256) void k_ln(const float* __restrict__ h, const float* __restrict__ g,
                     const float* __restrict__ bia, float* __restrict__ out){
  long z = blockIdx.y;
  int row = blockIdx.x*4 + (threadIdx.x >> 6);
  int lane = threadIdx.x & 63;
  const float4 x = *(const float4*)(h + z*PLANE + (long)row*DD + lane*4);
  float s  = x.x + x.y + x.z + x.w;
  float s2 = x.x*x.x + x.y*x.y + x.z*x.z + x.w*x.w;
  for(int o=1;o<64;o<<=1){ s += __shfl_xor(s,o); s2 += __shfl_xor(s2,o); }
  float m = s*(1.0f/256.0f);
  float var = s2*(1.0f/256.0f) - m*m;
  float r = rsqrtf(var + 1e-5f);
  const float4 gu = *(const float4*)(g + lane*4);
  const float4 bu = *(const float4*)(bia + lane*4);
  float4 o4;
  o4.x = (x.x-m)*r*gu.x + bu.x;
  o4.y = (x.y-m)*r*gu.y + bu.y;
  o4.z = (x.z-m)*r*gu.z + bu.z;
  o4.w = (x.w-m)*r*gu.w + bu.w;
  *(float4*)(out + z*PLANE + (long)row*DD + lane*4) = o4;
}

// ---------------- split-precision MFMA GEMM ----------------
// C[m][n] = sum_k A[m][k]*B[n][k]; each side either fp32 (split hi/lo on the
// fly, template flag true) or pre-split bf16 hi/lo planes (lo at +loOff elems).
// acc ≈ fp32: Ah*Bh + Al*Bh + Ah*Bl.
// epilogue: val = acc*rowscale[m] + bias[n];
//   accOut!=null: accOut[z][m][n] += val
//   else: fp32 section outs o0/o1/o2 (sec = gc>>8), relu+1e-6 per reluMask bit.
template<int BM, int BN, bool AF, bool BF>
__global__ __launch_bounds__(256) void k_mgemm(
    const void* __restrict__ Aab, long aStride, long aLoOff, int K,
    const void* __restrict__ Bab, long bStride, long bLoOff,
    const float* __restrict__ rowscale, long rsStride,
    const float* __restrict__ bias,
    float* __restrict__ o0, float* __restrict__ o1, float* __restrict__ o2,
    long oStride, int reluMask,
    float* __restrict__ accOut, long hStride)
{
  constexpr int WM = BM/2, WN = BN/2, MT = WM/16, NT = WN/16;
  __shared__ __align__(16) u16 Ahi[BM*32];
  __shared__ __align__(16) u16 Alo[BM*32];
  __shared__ __align__(16) u16 Bhi[BN*32];
  __shared__ __align__(16) u16 Blo[BN*32];
  const int t = threadIdx.x;
  const long z = blockIdx.z;
  const int rowTile = blockIdx.x*BM, colTile = blockIdx.y*BN;
  const int l = t & 63, w = t >> 6;
  const int wr = w >> 1, wc = w & 1;
  const int lm = l & 15, kq = l >> 4;

  f32x4 acc[MT][NT];
  #pragma unroll
  for(int mt=0;mt<MT;mt++)
    #pragma unroll
    for(int nt=0;nt<NT;nt++) acc[mt][nt] = (f32x4){0.f,0.f,0.f,0.f};

  constexpr int NLA = (BM*32)/(256*8);
  constexpr int NLB = (BN*32)/(256*8);

  for(int k0=0; k0<K; k0+=32){
    __syncthreads();
    #pragma unroll
    for(int li=0; li<NLA; li++){
      int flat = li*256 + t;
      int row = flat>>2, kg = (flat&3)*8;
      if constexpr (AF){
        const float* src = (const float*)Aab + z*aStride + (long)(rowTile+row)*K + k0 + kg;
        float4 v0 = ((const float4*)src)[0], v1 = ((const float4*)src)[1];
        float vs[8] = {v0.x,v0.y,v0.z,v0.w,v1.x,v1.y,v1.z,v1.w};
        us8 hv, lv;
        #pragma unroll
        for(int j=0;j<8;j++){ u16 hh = f2b(vs[j]); hv[j]=hh; lv[j]=f2b(vs[j]-b2f(hh)); }
        *(us8*)&Ahi[row*32+kg] = hv;
        *(us8*)&Alo[row*32+kg] = lv;
      } else {
        const u16* src = (const u16*)Aab + z*aStride + (long)(rowTile+row)*K + k0 + kg;
        *(us8*)&Ahi[row*32+kg] = *(const us8*)src;
        *(us8*)&Alo[row*32+kg] = *(const us8*)(src + aLoOff);
      }
    }
    #pragma unroll
    for(int li=0; li<NLB; li++){
      int flat = li*256 + t;
      int row = flat>>2, kg = (flat&3)*8;
      if constexpr (BF){
        const float* src = (const float*)Bab + z*bStride + (long)(colTile+row)*K + k0 + kg;
        float4 v0 = ((const float4*)src)[0], v1 = ((const float4*)src)[1];
        float vs[8] = {v0.x,v0.y,v0.z,v0.w,v1.x,v1.y,v1.z,v1.w};
        us8 hv, lv;
        #pragma unroll
        for(int j=0;j<8;j++){ u16 hh = f2b(vs[j]); hv[j]=hh; lv[j]=f2b(vs[j]-b2f(hh)); }
        *(us8*)&Bhi[row*32+kg] = hv;
        *(us8*)&Blo[row*32+kg] = lv;
      } else {
        const u16* src = (const u16*)Bab + z*bStride + (long)(colTile+row)*K + k0 + kg;
        *(us8*)&Bhi[row*32+kg] = *(const us8*)src;
        *(us8*)&Blo[row*32+kg] = *(const us8*)(src + bLoOff);
      }
    }
    __syncthreads();
    bf8 ah[MT], al[MT], bh[NT], bl[NT];
    #pragma unroll
    for(int mt=0;mt<MT;mt++){
      int idx = (wr*WM + mt*16 + lm)*32 + kq*8;
      ah[mt] = *(const bf8*)&Ahi[idx];
      al[mt] = *(const bf8*)&Alo[idx];
    }
    #pragma unroll
    for(int nt=0;nt<NT;nt++){
      int idx = (wc*WN + nt*16 + lm)*32 + kq*8;
      bh[nt] = *(const bf8*)&Bhi[idx];
      bl[nt] = *(const bf8*)&Blo[idx];
    }
    #pragma unroll
    for(int mt=0;mt<MT;mt++)
      #pragma unroll
      for(int nt=0;nt<NT;nt++){
        acc[mt][nt] = __builtin_amdgcn_mfma_f32_16x16x32_bf16(ah[mt], bh[nt], acc[mt][nt], 0, 0, 0);
        acc[mt][nt] = __builtin_amdgcn_mfma_f32_16x16x32_bf16(al[mt], bh[nt], acc[mt][nt], 0, 0, 0);
        acc[mt][nt] = __builtin_amdgcn_mfma_f32_16x16x32_bf16(ah[mt], bl[nt], acc[mt][nt], 0, 0, 0);
      }
  }

  // epilogue: C row = (lane>>4)*4 + reg, col = lane&15
  #pragma unroll
  for(int mt=0;mt<MT;mt++){
    #pragma unroll
    for(int r=0;r<4;r++){
      int gm = rowTile + wr*WM + mt*16 + kq*4 + r;
      float sc = rowscale ? rowscale[z*rsStride + gm] : 1.0f;
      if(accOut){
        float* hp = accOut + z*hStride + (long)gm*256;
        #pragma unroll
        for(int nt=0;nt<NT;nt++){
          int gc = colTile + wc*WN + nt*16 + lm;
          hp[gc] += acc[mt][nt][r]*sc + (bias ? bias[gc] : 0.f);
        }
      } else {
        #pragma unroll
        for(int nt=0;nt<NT;nt++){
          int gc = colTile + wc*WN + nt*16 + lm;
          int sec = gc >> 8;
          float* o = (sec==0) ? o0 : ((sec==1) ? o1 : o2);
          float val = acc[mt][nt][r]*sc + (bias ? bias[gc] : 0.f);
          if((reluMask >> sec) & 1) val = fmaxf(val, 0.f) + 1e-6f;
          o[z*oStride + (long)gm*256 + (gc & 255)] = val;
        }
      }
    }
  }
}

// ---------------- spmm gather fp32 (4 rows/block) ----------------
__global__ __launch_bounds__(256) void k_spmm(const float* __restrict__ in,
                       const int* __restrict__ offB, const int* __restrict__ srcB,
                       float* __restrict__ outp){
  long z = blockIdx.y;
  const float* ip = in + z*PLANE;
  float* op = outp + z*PLANE;
  const int* off = offB + z*(NN+1);
  const int* sE  = srcB + z*(long)NN*KK;
  int row = blockIdx.x*4 + (threadIdx.x >> 6);
  int d4 = (threadIdx.x & 63)*4;
  int s0 = off[row], s1 = off[row+1];
  float4 a = {0.f,0.f,0.f,0.f};
  for(int e=s0; e<s1; e++){
    int n = sE[e];
    const float4 u = *(const float4*)(ip + (long)n*DD + d4);
    a.x += u.x; a.y += u.y; a.z += u.z; a.w += u.w;
  }
  float4 o4;
  o4.x = a.x*INV6; o4.y = a.y*INV6; o4.z = a.z*INV6; o4.w = a.w*INV6;
  *(float4*)(op + (long)row*DD + d4) = o4;
}

// ---------------- rowdot rs = q . k3 (fp32) ----------------
__global__ __launch_bounds__(256) void k_rowdot(const float* __restrict__ qb, const float* __restrict__ kb,
                         float* __restrict__ rs){
  long z = blockIdx.y;
  int row = blockIdx.x*4 + (threadIdx.x >> 6);
  int lane = threadIdx.x & 63;
  const float4 a = *(const float4*)(qb + z*PLANE + (long)row*DD + lane*4);
  const float4 c = *(const float4*)(kb + z*PLANE + (long)row*DD + lane*4);
  float s = a.x*c.x + a.y*c.y + a.z*c.z + a.w*c.w;
  for(int o=1;o<64;o<<=1) s += __shfl_xor(s,o);
  if(lane==0) rs[z*NN + row] = s;
}

// ---------------- z = 1/(q . ksum + 1e-6) ----------------
__global__ __launch_bounds__(256) void k_zcalc(const float* __restrict__ qb, const float* __restrict__ ksum,
                        float* __restrict__ rs){
  long z = blockIdx.y;
  int row = blockIdx.x*4 + (threadIdx.x >> 6);
  int lane = threadIdx.x & 63;
  const float4 a = *(const float4*)(qb + z*PLANE + (long)row*DD + lane*4);
  const float4 c = *(const float4*)(ksum + z*DD + lane*4);
  float s = a.x*c.x + a.y*c.y + a.z*c.z + a.w*c.w;
  for(int o=1;o<64;o<<=1) s += __shfl_xor(s,o);
  if(lane==0) rs[z*NN + row] = 1.0f / (s + 1e-6f);
}

// ---- transpose fp32 [8192][256] -> pre-split hi/lo bf16 [256][8192] (+PLANE) ----
__global__ __launch_bounds__(256) void k_transp(const float* __restrict__ in, u16* __restrict__ outp){
  __shared__ float tile[64][65];
  long z = blockIdx.z;
  const float* ip = in + z*PLANE;
  u16* op = outp + z*2L*PLANE;
  int r0 = blockIdx.x*64, c0 = blockIdx.y*64;
  int t = threadIdx.x;
  {
    int r = t>>2, cg = (t&3)*16;
    #pragma unroll
    for(int j=0;j<4;j++)
      *(float4*)&tile[r][cg + j*4] = *(const float4*)(ip + (long)(r0+r)*DD + c0 + cg + j*4);
  }
  __syncthreads();
  {
    int c = t>>2, rg = t&3;
    us8 hv[2], lv[2];
    #pragma unroll
    for(int j=0;j<16;j++){
      float x = tile[rg*16+j][c];
      u16 hh = f2b(x);
      hv[j>>3][j&7] = hh;
      lv[j>>3][j&7] = f2b(x - b2f(hh));
    }
    u16* dhi = op + (long)(c0+c)*NN + r0 + rg*16;
    *(us8*)dhi = hv[0]; *(us8*)(dhi+8) = hv[1];
    u16* dlo = dhi + PLANE;
    *(us8*)dlo = lv[0]; *(us8*)(dlo+8) = lv[1];
  }
}

// ---- ksum[d] = sum_n k[n,d] from pre-split kT hi/lo ----
__global__ __launch_bounds__(256) void k_ksum(const u16* __restrict__ kT, float* __restrict__ ksum){
  long z = blockIdx.y;
  int d = blockIdx.x;
  const u16* ph = kT + z*2L*PLANE + (long)d*NN;
  const u16* pl = ph + PLANE;
  float s = 0.f;
  for(int i=threadIdx.x*4; i<NN; i+=1024){
    ushort4 a = *(const ushort4*)(ph+i);
    ushort4 b = *(const ushort4*)(pl+i);
    s += b2f(a.x)+b2f(a.y)+b2f(a.z)+b2f(a.w);
    s += b2f(b.x)+b2f(b.y)+b2f(b.z)+b2f(b.w);
  }
  for(int o=1;o<64;o<<=1) s += __shfl_xor(s,o);
  __shared__ float ws4[4];
  int w = threadIdx.x >> 6;
  if((threadIdx.x & 63)==0) ws4[w] = s;
  __syncthreads();
  if(threadIdx.x==0) ksum[z*DD + d] = ws4[0]+ws4[1]+ws4[2]+ws4[3];
}

// ---------------- head ----------------
__global__ __launch_bounds__(256) void k_head(const float* __restrict__ h, const float* __restrict__ hw,
                       const float* __restrict__ hb, float* __restrict__ out){
  long z = blockIdx.y;
  int row = blockIdx.x*4 + (threadIdx.x >> 6);
  int lane = threadIdx.x & 63;
  const float4 x = *(const float4*)(h + z*PLANE + (long)row*DD + lane*4);
  int d0 = lane*4;
  float a0 = x.x*hw[(d0+0)*3+0] + x.y*hw[(d0+1)*3+0] + x.z*hw[(d0+2)*3+0] + x.w*hw[(d0+3)*3+0];
  float a1 = x.x*hw[(d0+0)*3+1] + x.y*hw[(d0+1)*3+1] + x.z*hw[(d0+2)*3+1] + x.w*hw[(d0+3)*3+1];
  float a2 = x.x*hw[(d0+0)*3+2] + x.y*hw[(d0+1)*3+2] + x.z*hw[(d0+2)*3+2] + x.w*hw[(d0+3)*3+2];
  for(int o=1;o<64;o<<=1){
    a0 += __shfl_xor(a0,o); a1 += __shfl_xor(a1,o); a2 += __shfl_xor(a2,o);
  }
  if(lane==0){
    float* op = out + (z*NN + row)*3;
    op[0] = a0 + hb[0];
    op[1] = a1 + hb[1];
    op[2] = a2 + hb[2];
  }
}

struct Carve {
  float *h,*A,*Q,*Bp,*Cp,*kv,*w2t,*ksum,*rs;
  int *off,*cursor,*srcE;
  u16 *wt_gqkv,*wt_aqkv,*wt_gout,*wt_aout;
  size_t total;
};

static Carve carve(char* base, int C){
  Carve c;
  size_t cur = 0;
  auto bump = [&](size_t bytes)->char*{
    char* p = base ? base + cur : (char*)0;
    cur += (bytes + 255) & ~(size_t)255;
    return p;
  };
  c.h    = (float*)bump((size_t)C*PLANE*4);
  c.A    = (float*)bump((size_t)C*PLANE*4);   // also reused as u16 hi/lo kT
  c.Q    = (float*)bump((size_t)C*PLANE*4);
  c.Bp   = (float*)bump((size_t)C*PLANE*4);   // also reused as u16 hi/lo vT
  c.Cp   = (float*)bump((size_t)C*PLANE*4);
  c.kv   = (float*)bump((size_t)C*DD*DD*4);
  c.w2t  = (float*)bump((size_t)C*DD*DD*4);
  c.ksum = (float*)bump((size_t)C*DD*4);
  c.rs   = (float*)bump((size_t)C*NN*4);
  c.off  = (int*)bump((size_t)BB*(NN+1)*4);
  c.cursor=(int*)bump((size_t)BB*(NN+1)*4);
  c.srcE = (int*)bump((size_t)NE*4);
  c.wt_gqkv = (u16*)bump((size_t)LL*2*768*256*2);
  c.wt_aqkv = (u16*)bump((size_t)LL*2*768*256*2);
  c.wt_gout = (u16*)bump((size_t)LL*2*256*256*2);
  c.wt_aout = (u16*)bump((size_t)LL*2*256*256*2);
  c.total = cur;
  return c;
}

extern "C" void kernel_launch(void* const* d_in, const int* in_sizes, int n_in,
                              void* d_out, int out_size, void* d_ws, size_t ws_size,
                              hipStream_t stream)
{
  const float* x        = (const float*)d_in[0];
  const int*   knn      = (const int*)d_in[1];
  const float* emb_w    = (const float*)d_in[2];
  const float* emb_b    = (const float*)d_in[3];
  const float* norm_g   = (const float*)d_in[4];
  const float* norm_b   = (const float*)d_in[5];
  const float* grf_qkv  = (const float*)d_in[6];
  const float* grf_outw = (const float*)d_in[7];
  const float* grf_outb = (const float*)d_in[8];
  const float* attn_qkv = (const float*)d_in[9];
  const float* attn_outw= (const float*)d_in[10];
  const float* attn_outb= (const float*)d_in[11];
  const float* head_w   = (const float*)d_in[12];
  const float* head_b   = (const float*)d_in[13];
  float* out = (float*)d_out;

  int C = 1;
  for(int cc=BB; cc>=1; cc>>=1){ if(carve(nullptr, cc).total <= ws_size){ C = cc; break; } }
  Carve ws = carve((char*)d_ws, C);

  // ---- weight prep (hi/lo bf16, transposed to [N][K]) ----
  k_prepw<<<dim3(768, LL), 256, 0, stream>>>(grf_qkv,  ws.wt_gqkv, 768);
  k_prepw<<<dim3(768, LL), 256, 0, stream>>>(attn_qkv, ws.wt_aqkv, 768);
  k_prepw<<<dim3(256, LL), 256, 0, stream>>>(grf_outw, ws.wt_gout, 256);
  k_prepw<<<dim3(256, LL), 256, 0, stream>>>(attn_outw,ws.wt_aout, 256);

  // ---- CSR build for all batches ----
  hipMemsetAsync(ws.off, 0, (size_t)BB*(NN+1)*sizeof(int), stream);
  k_count<<<dim3((NE+255)/256), 256, 0, stream>>>(knn, ws.off);
  k_scan<<<dim3(BB), 1024, 0, stream>>>(ws.off);
  hipMemcpyAsync(ws.cursor, ws.off, (size_t)BB*(NN+1)*sizeof(int), hipMemcpyDeviceToDevice, stream);
  k_fill<<<dim3((NE+255)/256), 256, 0, stream>>>(knn, ws.cursor, ws.srcE);

  const long PL = PLANE;
  for(int b0=0; b0<BB; b0+=C){
    const int* offB  = ws.off  + (long)b0*(NN+1);
    const int* srcB  = ws.srcE + (long)b0*NN*KK;

    k_embed<<<dim3(NN, C), 256, 0, stream>>>(x + (long)b0*NN*3, emb_w, emb_b, ws.h);

    for(int i=0; i<LL; i++){
      // ===== GRF sublayer =====
      k_ln<<<dim3(NN/4, C), 256, 0, stream>>>(ws.h, norm_g + (2*i)*DD, norm_b + (2*i)*DD, ws.A);
      k_mgemm<128,128,true,false><<<dim3(64, 6, C), 256, 0, stream>>>(
          ws.A, PL, 0, 256,
          ws.wt_gqkv + (long)i*2*768*256, 0, (long)768*256,
          nullptr, 0, nullptr,
          ws.Q, ws.Bp, ws.Cp, PL, 0, nullptr, 0);
      // k hops: Bp->A->Bp->A (k3 in A)
      k_spmm<<<dim3(NN/4, C), 256, 0, stream>>>(ws.Bp, offB, srcB, ws.A);
      k_spmm<<<dim3(NN/4, C), 256, 0, stream>>>(ws.A,  offB, srcB, ws.Bp);
      k_spmm<<<dim3(NN/4, C), 256, 0, stream>>>(ws.Bp, offB, srcB, ws.A);
      k_rowdot<<<dim3(NN/4, C), 256, 0, stream>>>(ws.Q, ws.A, ws.rs);
      // v hops: Cp->A->Cp->A (v3 in A)
      k_spmm<<<dim3(NN/4, C), 256, 0, stream>>>(ws.Cp, offB, srcB, ws.A);
      k_spmm<<<dim3(NN/4, C), 256, 0, stream>>>(ws.A,  offB, srcB, ws.Cp);
      k_spmm<<<dim3(NN/4, C), 256, 0, stream>>>(ws.Cp, offB, srcB, ws.A);
      // h += (rs * v3) @ grf_outw + grf_outb
      k_mgemm<128,128,true,false><<<dim3(64, 2, C), 256, 0, stream>>>(
          ws.A, PL, 0, 256,
          ws.wt_gout + (long)i*2*256*256, 0, (long)256*256,
          ws.rs, NN, grf_outb + (long)i*DD,
          nullptr, nullptr, nullptr, 0, 0, ws.h, PL);

      // ===== linear attention sublayer =====
      k_ln<<<dim3(NN/4, C), 256, 0, stream>>>(ws.h, norm_g + (2*i+1)*DD, norm_b + (2*i+1)*DD, ws.A);
      k_mgemm<128,128,true,false><<<dim3(64, 6, C), 256, 0, stream>>>(
          ws.A, PL, 0, 256,
          ws.wt_aqkv + (long)i*2*768*256, 0, (long)768*256,
          nullptr, 0, nullptr,
          ws.Q, ws.Bp, ws.Cp, PL, 3 /* relu+1e-6 on q,k */, nullptr, 0);
      // kT = split(Bp^T) -> A ; vT = split(Cp^T) -> Bp
      k_transp<<<dim3(NN/64, DD/64, C), 256, 0, stream>>>(ws.Bp, (u16*)ws.A);
      k_transp<<<dim3(NN/64, DD/64, C), 256, 0, stream>>>(ws.Cp, (u16*)ws.Bp);
      k_ksum<<<dim3(DD, C), 256, 0, stream>>>((const u16*)ws.A, ws.ksum);
      // kv[d][e] = sum_n kT[d][n] * vT[e][n]
      k_mgemm<64,64,false,false><<<dim3(4, 4, C), 256, 0, stream>>>(
          (const u16*)ws.A, 2L*PL, PL, NN,
          (const u16*)ws.Bp, 2L*PL, PL,
          nullptr, 0, nullptr,
          ws.kv, nullptr, nullptr, (long)DD*DD, 0, nullptr, 0);
      // w2t[n][d] = sum_e Wout^T[n][e] * kv[d][e]
      k_mgemm<64,64,false,true><<<dim3(4, 4, C), 256, 0, stream>>>(
          ws.wt_aout + (long)i*2*256*256, 0, (long)256*256, 256,
          ws.kv, (long)DD*DD, 0,
          nullptr, 0, nullptr,
          ws.w2t, nullptr, nullptr, (long)DD*DD, 0, nullptr, 0);
      k_zcalc<<<dim3(NN/4, C), 256, 0, stream>>>(ws.Q, ws.ksum, ws.rs);
      // h += (z * q) @ w2 + attn_outb
      k_mgemm<128,128,true,true><<<dim3(64, 2, C), 256, 0, stream>>>(
          ws.Q, PL, 0, 256,
          ws.w2t, (long)DD*DD, 0,
          ws.rs, NN, attn_outb + (long)i*DD,
          nullptr, nullptr, nullptr, 0, 0, ws.h, PL);
    }

    k_head<<<dim3(NN/4, C), 256, 0, stream>>>(ws.h, head_w, head_b, out + (long)b0*NN*3);
  }
}

// Round 7
// 5385.916 us; speedup vs baseline: 2.5685x; 1.2276x over previous
//
#include <hip/hip_runtime.h>
#include <hip/hip_bf16.h>

#define BB 8
#define NN 8192
#define KK 6
#define DD 256
#define LL 5
#define NE (BB*NN*KK)       // 393216
#define PLANE (NN*DD)       // 2097152 elems per batch
#define INV6 (1.0f/6.000001f)

typedef unsigned short u16;
typedef __attribute__((ext_vector_type(8))) short bf8;     // 8 bf16 (4 VGPRs)
typedef __attribute__((ext_vector_type(8))) unsigned short us8;
typedef __attribute__((ext_vector_type(4))) float f32x4;

__device__ __forceinline__ float b2f(u16 u){
  union { unsigned int i; float f; } c; c.i = ((unsigned int)u) << 16; return c.f;
}
__device__ __forceinline__ u16 f2b(float f){
  union { float f; unsigned int i; } c; c.f = f;
  unsigned int x = c.i;
  x += 0x7fffu + ((x >> 16) & 1u);
  return (u16)(x >> 16);
}

// ---------------- CSR build ----------------
__global__ void k_count(const int* __restrict__ knn, int* __restrict__ off){
  int e = blockIdx.x*256 + threadIdx.x;
  if(e >= NE) return;
  int b = e / (NN*KK);
  int j = knn[e];
  atomicAdd(&off[b*(NN+1) + 1 + j], 1);
}

__global__ __launch_bounds__(1024) void k_scan(int* __restrict__ offAll){
  __shared__ int lds[1024];
  __shared__ int carry_s;
  int* off = offAll + blockIdx.x*(NN+1);
  const int len = NN+1;
  int t = threadIdx.x;
  if(t==0) carry_s = 0;
  __syncthreads();
  for(int base=0; base<len; base+=1024){
    int x = (base+t < len) ? off[base+t] : 0;
    lds[t] = x; __syncthreads();
    for(int s=1; s<1024; s<<=1){
      int v = (t>=s) ? lds[t-s] : 0;
      __syncthreads();
      lds[t] += v;
      __syncthreads();
    }
    int incl = lds[t];
    int carry = carry_s;
    __syncthreads();
    if(base+t < len) off[base+t] = incl + carry;
    if(t==1023) carry_s = carry + incl;
    __syncthreads();
  }
}

__global__ void k_fill(const int* __restrict__ knn, int* __restrict__ cursor, int* __restrict__ srcE){
  int e = blockIdx.x*256 + threadIdx.x;
  if(e >= NE) return;
  int b = e / (NN*KK);
  int n = (e % (NN*KK)) / KK;
  int j = knn[e];
  int pos = atomicAdd(&cursor[b*(NN+1) + j], 1);
  srcE[(long)b*NN*KK + pos] = n;
}

// ---- weight prep: W fp32 [L][256][N] -> Wt hi/lo bf16 [L][2][N][256] ----
__global__ __launch_bounds__(256) void k_prepw(const float* __restrict__ W, u16* __restrict__ Wt, int N){
  int n = blockIdx.x, l = blockIdx.y, k = threadIdx.x;
  float x = W[((long)l*256 + k)*N + n];
  u16 h = f2b(x);
  Wt[(((long)l*2 + 0)*N + n)*256 + k] = h;
  Wt[(((long)l*2 + 1)*N + n)*256 + k] = f2b(x - b2f(h));
}

// ---------------- embed ----------------
__global__ __launch_bounds__(256) void k_embed(const float* __restrict__ x, const float* __restrict__ ew,
                        const float* __restrict__ eb, float* __restrict__ h){
  int g = blockIdx.x, z = blockIdx.y, d = threadIdx.x;
  const float* xp = x + ((long)z*NN + g)*3;
  h[(long)z*PLANE + (long)g*DD + d] = xp[0]*ew[0*DD+d] + xp[1]*ew[1*DD+d] + xp[2]*ew[2*DD+d] + eb[d];
}

// ---------------- layernorm fp32 -> PRE-SPLIT hi/lo bf16 planes ----------------
__global__ __launch_bounds__(256) void k_ln(const float* __restrict__ h, const float* __restrict__ g,
                     const float* __restrict__ bia, u16* __restrict__ out){
  long z = blockIdx.y;
  int row = blockIdx.x*4 + (threadIdx.x >> 6);
  int lane = threadIdx.x & 63;
  const float4 x = *(const float4*)(h + z*PLANE + (long)row*DD + lane*4);
  float s  = x.x + x.y + x.z + x.w;
  float s2 = x.x*x.x + x.y*x.y + x.z*x.z + x.w*x.w;
  for(int o=1;o<64;o<<=1){ s += __shfl_xor(s,o); s2 += __shfl_xor(s2,o); }
  float m = s*(1.0f/256.0f);
  float var = s2*(1.0f/256.0f) - m*m;
  float r = rsqrtf(var + 1e-5f);
  const float4 gu = *(const float4*)(g + lane*4);
  const float4 bu = *(const float4*)(bia + lane*4);
  float v[4];
  v[0] = (x.x-m)*r*gu.x + bu.x;
  v[1] = (x.y-m)*r*gu.y + bu.y;
  v[2] = (x.z-m)*r*gu.z + bu.z;
  v[3] = (x.w-m)*r*gu.w + bu.w;
  ushort4 hv, lv;
  u16 hh;
  hh = f2b(v[0]); hv.x = hh; lv.x = f2b(v[0]-b2f(hh));
  hh = f2b(v[1]); hv.y = hh; lv.y = f2b(v[1]-b2f(hh));
  hh = f2b(v[2]); hv.z = hh; lv.z = f2b(v[2]-b2f(hh));
  hh = f2b(v[3]); hv.w = hh; lv.w = f2b(v[3]-b2f(hh));
  u16* op = out + z*2L*PLANE + (long)row*DD + lane*4;
  *(ushort4*)op = hv;
  *(ushort4*)(op + PLANE) = lv;
}

// ---------------- split-precision MFMA GEMM ----------------
// C[m][n] = sum_k A[m][k]*B[n][k]; side fp32 (split on the fly, flag true) or
// pre-split bf16 hi/lo (lo at +loOff elems). acc ≈ Ah*Bh + Al*Bh + Ah*Bl.
// kSplit>1: K chunked over blockIdx.z%kSplit, fp32 atomicAdd into accOut.
#define LR 40   // padded LDS row stride (u16): 80B = 16B-aligned, 2-way banks only
template<int BM, int BN, bool AF, bool BF>
__global__ __launch_bounds__(256) void k_mgemm(
    const void* __restrict__ Aab, long aStride, long aLoOff, int K, int kSplit,
    const void* __restrict__ Bab, long bStride, long bLoOff,
    const float* __restrict__ rowscale, long rsStride,
    const float* __restrict__ bias,
    float* __restrict__ o0, float* __restrict__ o1, float* __restrict__ o2,
    long oStride, int reluMask,
    float* __restrict__ accOut, long hStride)
{
  constexpr int WM = BM/2, WN = BN/2, MT = WM/16, NT = WN/16;
  __shared__ __align__(16) u16 Ahi[BM*LR];
  __shared__ __align__(16) u16 Alo[BM*LR];
  __shared__ __align__(16) u16 Bhi[BN*LR];
  __shared__ __align__(16) u16 Blo[BN*LR];
  const int t = threadIdx.x;
  const int nz = blockIdx.z;
  const long z = nz / kSplit;
  const int chunk = nz % kSplit;
  const int kLen = K / kSplit, kLo = chunk * kLen;
  const int rowTile = blockIdx.x*BM, colTile = blockIdx.y*BN;
  const int l = t & 63, w = t >> 6;
  const int wr = w >> 1, wc = w & 1;
  const int lm = l & 15, kq = l >> 4;

  f32x4 acc[MT][NT];
  #pragma unroll
  for(int mt=0;mt<MT;mt++)
    #pragma unroll
    for(int nt=0;nt<NT;nt++) acc[mt][nt] = (f32x4){0.f,0.f,0.f,0.f};

  constexpr int NLA = (BM*32)/(256*8);
  constexpr int NLB = (BN*32)/(256*8);

  for(int k0=kLo; k0<kLo+kLen; k0+=32){
    __syncthreads();
    #pragma unroll
    for(int li=0; li<NLA; li++){
      int flat = li*256 + t;
      int row = flat>>2, kg = (flat&3)*8;
      if constexpr (AF){
        const float* src = (const float*)Aab + z*aStride + (long)(rowTile+row)*K + k0 + kg;
        float4 v0 = ((const float4*)src)[0], v1 = ((const float4*)src)[1];
        float vs[8] = {v0.x,v0.y,v0.z,v0.w,v1.x,v1.y,v1.z,v1.w};
        us8 hv, lv;
        #pragma unroll
        for(int j=0;j<8;j++){ u16 hh = f2b(vs[j]); hv[j]=hh; lv[j]=f2b(vs[j]-b2f(hh)); }
        *(us8*)&Ahi[row*LR+kg] = hv;
        *(us8*)&Alo[row*LR+kg] = lv;
      } else {
        const u16* src = (const u16*)Aab + z*aStride + (long)(rowTile+row)*K + k0 + kg;
        *(us8*)&Ahi[row*LR+kg] = *(const us8*)src;
        *(us8*)&Alo[row*LR+kg] = *(const us8*)(src + aLoOff);
      }
    }
    #pragma unroll
    for(int li=0; li<NLB; li++){
      int flat = li*256 + t;
      int row = flat>>2, kg = (flat&3)*8;
      if constexpr (BF){
        const float* src = (const float*)Bab + z*bStride + (long)(colTile+row)*K + k0 + kg;
        float4 v0 = ((const float4*)src)[0], v1 = ((const float4*)src)[1];
        float vs[8] = {v0.x,v0.y,v0.z,v0.w,v1.x,v1.y,v1.z,v1.w};
        us8 hv, lv;
        #pragma unroll
        for(int j=0;j<8;j++){ u16 hh = f2b(vs[j]); hv[j]=hh; lv[j]=f2b(vs[j]-b2f(hh)); }
        *(us8*)&Bhi[row*LR+kg] = hv;
        *(us8*)&Blo[row*LR+kg] = lv;
      } else {
        const u16* src = (const u16*)Bab + z*bStride + (long)(colTile+row)*K + k0 + kg;
        *(us8*)&Bhi[row*LR+kg] = *(const us8*)src;
        *(us8*)&Blo[row*LR+kg] = *(const us8*)(src + bLoOff);
      }
    }
    __syncthreads();
    bf8 ah[MT], al[MT], bh[NT], bl[NT];
    #pragma unroll
    for(int mt=0;mt<MT;mt++){
      int idx = (wr*WM + mt*16 + lm)*LR + kq*8;
      ah[mt] = *(const bf8*)&Ahi[idx];
      al[mt] = *(const bf8*)&Alo[idx];
    }
    #pragma unroll
    for(int nt=0;nt<NT;nt++){
      int idx = (wc*WN + nt*16 + lm)*LR + kq*8;
      bh[nt] = *(const bf8*)&Bhi[idx];
      bl[nt] = *(const bf8*)&Blo[idx];
    }
    #pragma unroll
    for(int mt=0;mt<MT;mt++)
      #pragma unroll
      for(int nt=0;nt<NT;nt++){
        acc[mt][nt] = __builtin_amdgcn_mfma_f32_16x16x32_bf16(ah[mt], bh[nt], acc[mt][nt], 0, 0, 0);
        acc[mt][nt] = __builtin_amdgcn_mfma_f32_16x16x32_bf16(al[mt], bh[nt], acc[mt][nt], 0, 0, 0);
        acc[mt][nt] = __builtin_amdgcn_mfma_f32_16x16x32_bf16(ah[mt], bl[nt], acc[mt][nt], 0, 0, 0);
      }
  }

  // epilogue: C row = (lane>>4)*4 + reg, col = lane&15
  #pragma unroll
  for(int mt=0;mt<MT;mt++){
    #pragma unroll
    for(int r=0;r<4;r++){
      int gm = rowTile + wr*WM + mt*16 + kq*4 + r;
      float sc = rowscale ? rowscale[z*rsStride + gm] : 1.0f;
      if(accOut){
        float* hp = accOut + z*hStride + (long)gm*256;
        if(kSplit > 1){
          #pragma unroll
          for(int nt=0;nt<NT;nt++){
            int gc = colTile + wc*WN + nt*16 + lm;
            atomicAdd(&hp[gc], acc[mt][nt][r]);
          }
        } else {
          #pragma unroll
          for(int nt=0;nt<NT;nt++){
            int gc = colTile + wc*WN + nt*16 + lm;
            hp[gc] += acc[mt][nt][r]*sc + (bias ? bias[gc] : 0.f);
          }
        }
      } else {
        #pragma unroll
        for(int nt=0;nt<NT;nt++){
          int gc = colTile + wc*WN + nt*16 + lm;
          int sec = gc >> 8;
          float* o = (sec==0) ? o0 : ((sec==1) ? o1 : o2);
          float val = acc[mt][nt][r]*sc + (bias ? bias[gc] : 0.f);
          if((reluMask >> sec) & 1) val = fmaxf(val, 0.f) + 1e-6f;
          o[z*oStride + (long)gm*256 + (gc & 255)] = val;
        }
      }
    }
  }
}

// ------------- fused k+v spmm gather (fp32, 2-edge unroll, 4 gathers in flight) -------------
__global__ __launch_bounds__(256) void k_spmm2(
    const float* __restrict__ kin, const float* __restrict__ vin,
    const int* __restrict__ offB, const int* __restrict__ srcB,
    float* __restrict__ kout, float* __restrict__ vout){
  long z = blockIdx.y;
  const float* kp = kin + z*PLANE;
  const float* vp = vin + z*PLANE;
  const int* off = offB + z*(NN+1);
  const int* sE  = srcB + z*(long)NN*KK;
  int row = blockIdx.x*4 + (threadIdx.x >> 6);
  int d4 = (threadIdx.x & 63)*4;
  int s0 = off[row], s1 = off[row+1];
  float4 ak = {0.f,0.f,0.f,0.f};
  float4 av = {0.f,0.f,0.f,0.f};
  int e = s0;
  for(; e+1 < s1; e += 2){
    int n0 = sE[e], n1 = sE[e+1];
    float4 k0 = *(const float4*)(kp + (long)n0*DD + d4);
    float4 k1 = *(const float4*)(kp + (long)n1*DD + d4);
    float4 v0 = *(const float4*)(vp + (long)n0*DD + d4);
    float4 v1 = *(const float4*)(vp + (long)n1*DD + d4);
    ak.x += k0.x + k1.x; ak.y += k0.y + k1.y; ak.z += k0.z + k1.z; ak.w += k0.w + k1.w;
    av.x += v0.x + v1.x; av.y += v0.y + v1.y; av.z += v0.z + v1.z; av.w += v0.w + v1.w;
  }
  if(e < s1){
    int n0 = sE[e];
    float4 k0 = *(const float4*)(kp + (long)n0*DD + d4);
    float4 v0 = *(const float4*)(vp + (long)n0*DD + d4);
    ak.x += k0.x; ak.y += k0.y; ak.z += k0.z; ak.w += k0.w;
    av.x += v0.x; av.y += v0.y; av.z += v0.z; av.w += v0.w;
  }
  float4 ok = {ak.x*INV6, ak.y*INV6, ak.z*INV6, ak.w*INV6};
  float4 ov = {av.x*INV6, av.y*INV6, av.z*INV6, av.w*INV6};
  *(float4*)(kout + z*PLANE + (long)row*DD + d4) = ok;
  *(float4*)(vout + z*PLANE + (long)row*DD + d4) = ov;
}

// ---------------- rowdot rs = q . k3 (fp32) ----------------
__global__ __launch_bounds__(256) void k_rowdot(const float* __restrict__ qb, const float* __restrict__ kb,
                         float* __restrict__ rs){
  long z = blockIdx.y;
  int row = blockIdx.x*4 + (threadIdx.x >> 6);
  int lane = threadIdx.x & 63;
  const float4 a = *(const float4*)(qb + z*PLANE + (long)row*DD + lane*4);
  const float4 c = *(const float4*)(kb + z*PLANE + (long)row*DD + lane*4);
  float s = a.x*c.x + a.y*c.y + a.z*c.z + a.w*c.w;
  for(int o=1;o<64;o<<=1) s += __shfl_xor(s,o);
  if(lane==0) rs[z*NN + row] = s;
}

// ---------------- z = 1/(q . ksum + 1e-6) ----------------
__global__ __launch_bounds__(256) void k_zcalc(const float* __restrict__ qb, const float* __restrict__ ksum,
                        float* __restrict__ rs){
  long z = blockIdx.y;
  int row = blockIdx.x*4 + (threadIdx.x >> 6);
  int lane = threadIdx.x & 63;
  const float4 a = *(const float4*)(qb + z*PLANE + (long)row*DD + lane*4);
  const float4 c = *(const float4*)(ksum + z*DD + lane*4);
  float s = a.x*c.x + a.y*c.y + a.z*c.z + a.w*c.w;
  for(int o=1;o<64;o<<=1) s += __shfl_xor(s,o);
  if(lane==0) rs[z*NN + row] = 1.0f / (s + 1e-6f);
}

// ---- transpose fp32 [8192][256] -> pre-split hi/lo bf16 [256][8192] (+PLANE) ----
__global__ __launch_bounds__(256) void k_transp(const float* __restrict__ in, u16* __restrict__ outp){
  __shared__ float tile[64][65];
  long z = blockIdx.z;
  const float* ip = in + z*PLANE;
  u16* op = outp + z*2L*PLANE;
  int r0 = blockIdx.x*64, c0 = blockIdx.y*64;
  int t = threadIdx.x;
  {
    int r = t>>2, cg = (t&3)*16;
    #pragma unroll
    for(int j=0;j<4;j++)
      *(float4*)&tile[r][cg + j*4] = *(const float4*)(ip + (long)(r0+r)*DD + c0 + cg + j*4);
  }
  __syncthreads();
  {
    int c = t>>2, rg = t&3;
    us8 hv[2], lv[2];
    #pragma unroll
    for(int j=0;j<16;j++){
      float x = tile[rg*16+j][c];
      u16 hh = f2b(x);
      hv[j>>3][j&7] = hh;
      lv[j>>3][j&7] = f2b(x - b2f(hh));
    }
    u16* dhi = op + (long)(c0+c)*NN + r0 + rg*16;
    *(us8*)dhi = hv[0]; *(us8*)(dhi+8) = hv[1];
    u16* dlo = dhi + PLANE;
    *(us8*)dlo = lv[0]; *(us8*)(dlo+8) = lv[1];
  }
}

// ---- ksum[d] = sum_n k[n,d] from pre-split kT hi/lo ----
__global__ __launch_bounds__(256) void k_ksum(const u16* __restrict__ kT, float* __restrict__ ksum){
  long z = blockIdx.y;
  int d = blockIdx.x;
  const u16* ph = kT + z*2L*PLANE + (long)d*NN;
  const u16* pl = ph + PLANE;
  float s = 0.f;
  for(int i=threadIdx.x*4; i<NN; i+=1024){
    ushort4 a = *(const ushort4*)(ph+i);
    ushort4 b = *(const ushort4*)(pl+i);
    s += b2f(a.x)+b2f(a.y)+b2f(a.z)+b2f(a.w);
    s += b2f(b.x)+b2f(b.y)+b2f(b.z)+b2f(b.w);
  }
  for(int o=1;o<64;o<<=1) s += __shfl_xor(s,o);
  __shared__ float ws4[4];
  int w = threadIdx.x >> 6;
  if((threadIdx.x & 63)==0) ws4[w] = s;
  __syncthreads();
  if(threadIdx.x==0) ksum[z*DD + d] = ws4[0]+ws4[1]+ws4[2]+ws4[3];
}

// ---------------- head ----------------
__global__ __launch_bounds__(256) void k_head(const float* __restrict__ h, const float* __restrict__ hw,
                       const float* __restrict__ hb, float* __restrict__ out){
  long z = blockIdx.y;
  int row = blockIdx.x*4 + (threadIdx.x >> 6);
  int lane = threadIdx.x & 63;
  const float4 x = *(const float4*)(h + z*PLANE + (long)row*DD + lane*4);
  int d0 = lane*4;
  float a0 = x.x*hw[(d0+0)*3+0] + x.y*hw[(d0+1)*3+0] + x.z*hw[(d0+2)*3+0] + x.w*hw[(d0+3)*3+0];
  float a1 = x.x*hw[(d0+0)*3+1] + x.y*hw[(d0+1)*3+1] + x.z*hw[(d0+2)*3+1] + x.w*hw[(d0+3)*3+1];
  float a2 = x.x*hw[(d0+0)*3+2] + x.y*hw[(d0+1)*3+2] + x.z*hw[(d0+2)*3+2] + x.w*hw[(d0+3)*3+2];
  for(int o=1;o<64;o<<=1){
    a0 += __shfl_xor(a0,o); a1 += __shfl_xor(a1,o); a2 += __shfl_xor(a2,o);
  }
  if(lane==0){
    float* op = out + (z*NN + row)*3;
    op[0] = a0 + hb[0];
    op[1] = a1 + hb[1];
    op[2] = a2 + hb[2];
  }
}

struct Carve {
  float *h,*S,*T,*Q,*Bp,*Cp,*kv,*w2t,*ksum,*rs;
  int *off,*cursor,*srcE;
  u16 *wt_gqkv,*wt_aqkv,*wt_gout,*wt_aout;
  size_t total;
};

static Carve carve(char* base, int C){
  Carve c;
  size_t cur = 0;
  auto bump = [&](size_t bytes)->char*{
    char* p = base ? base + cur : (char*)0;
    cur += (bytes + 255) & ~(size_t)255;
    return p;
  };
  c.h    = (float*)bump((size_t)C*PLANE*4);
  c.S    = (float*)bump((size_t)C*PLANE*4);   // split u16 hi/lo (LN out, kT) OR fp32 scratch
  c.T    = (float*)bump((size_t)C*PLANE*4);   // fp32 scratch OR split vT
  c.Q    = (float*)bump((size_t)C*PLANE*4);
  c.Bp   = (float*)bump((size_t)C*PLANE*4);
  c.Cp   = (float*)bump((size_t)C*PLANE*4);
  c.kv   = (float*)bump((size_t)C*DD*DD*4);
  c.w2t  = (float*)bump((size_t)C*DD*DD*4);
  c.ksum = (float*)bump((size_t)C*DD*4);
  c.rs   = (float*)bump((size_t)C*NN*4);
  c.off  = (int*)bump((size_t)BB*(NN+1)*4);
  c.cursor=(int*)bump((size_t)BB*(NN+1)*4);
  c.srcE = (int*)bump((size_t)NE*4);
  c.wt_gqkv = (u16*)bump((size_t)LL*2*768*256*2);
  c.wt_aqkv = (u16*)bump((size_t)LL*2*768*256*2);
  c.wt_gout = (u16*)bump((size_t)LL*2*256*256*2);
  c.wt_aout = (u16*)bump((size_t)LL*2*256*256*2);
  c.total = cur;
  return c;
}

extern "C" void kernel_launch(void* const* d_in, const int* in_sizes, int n_in,
                              void* d_out, int out_size, void* d_ws, size_t ws_size,
                              hipStream_t stream)
{
  const float* x        = (const float*)d_in[0];
  const int*   knn      = (const int*)d_in[1];
  const float* emb_w    = (const float*)d_in[2];
  const float* emb_b    = (const float*)d_in[3];
  const float* norm_g   = (const float*)d_in[4];
  const float* norm_b   = (const float*)d_in[5];
  const float* grf_qkv  = (const float*)d_in[6];
  const float* grf_outw = (const float*)d_in[7];
  const float* grf_outb = (const float*)d_in[8];
  const float* attn_qkv = (const float*)d_in[9];
  const float* attn_outw= (const float*)d_in[10];
  const float* attn_outb= (const float*)d_in[11];
  const float* head_w   = (const float*)d_in[12];
  const float* head_b   = (const float*)d_in[13];
  float* out = (float*)d_out;

  int C = 1;
  for(int cc=BB; cc>=1; cc>>=1){ if(carve(nullptr, cc).total <= ws_size){ C = cc; break; } }
  Carve ws = carve((char*)d_ws, C);

  // ---- weight prep (hi/lo bf16, transposed to [N][K]) ----
  k_prepw<<<dim3(768, LL), 256, 0, stream>>>(grf_qkv,  ws.wt_gqkv, 768);
  k_prepw<<<dim3(768, LL), 256, 0, stream>>>(attn_qkv, ws.wt_aqkv, 768);
  k_prepw<<<dim3(256, LL), 256, 0, stream>>>(grf_outw, ws.wt_gout, 256);
  k_prepw<<<dim3(256, LL), 256, 0, stream>>>(attn_outw,ws.wt_aout, 256);

  // ---- CSR build for all batches ----
  hipMemsetAsync(ws.off, 0, (size_t)BB*(NN+1)*sizeof(int), stream);
  k_count<<<dim3((NE+255)/256), 256, 0, stream>>>(knn, ws.off);
  k_scan<<<dim3(BB), 1024, 0, stream>>>(ws.off);
  hipMemcpyAsync(ws.cursor, ws.off, (size_t)BB*(NN+1)*sizeof(int), hipMemcpyDeviceToDevice, stream);
  k_fill<<<dim3((NE+255)/256), 256, 0, stream>>>(knn, ws.cursor, ws.srcE);

  const long PL = PLANE;
  for(int b0=0; b0<BB; b0+=C){
    const int* offB  = ws.off  + (long)b0*(NN+1);
    const int* srcB  = ws.srcE + (long)b0*NN*KK;

    k_embed<<<dim3(NN, C), 256, 0, stream>>>(x + (long)b0*NN*3, emb_w, emb_b, ws.h);

    for(int i=0; i<LL; i++){
      // ===== GRF sublayer =====
      k_ln<<<dim3(NN/4, C), 256, 0, stream>>>(ws.h, norm_g + (2*i)*DD, norm_b + (2*i)*DD, (u16*)ws.S);
      k_mgemm<128,128,false,false><<<dim3(64, 6, C), 256, 0, stream>>>(
          (const u16*)ws.S, 2L*PL, PL, 256, 1,
          ws.wt_gqkv + (long)i*2*768*256, 0, (long)768*256,
          nullptr, 0, nullptr,
          ws.Q, ws.Bp, ws.Cp, PL, 0, nullptr, 0);
      // fused k/v hops: (Bp,Cp)->(S,T)->(Bp,Cp)->(S,T); k3 in S, v3 in T
      k_spmm2<<<dim3(NN/4, C), 256, 0, stream>>>(ws.Bp, ws.Cp, offB, srcB, ws.S, ws.T);
      k_spmm2<<<dim3(NN/4, C), 256, 0, stream>>>(ws.S,  ws.T,  offB, srcB, ws.Bp, ws.Cp);
      k_spmm2<<<dim3(NN/4, C), 256, 0, stream>>>(ws.Bp, ws.Cp, offB, srcB, ws.S, ws.T);
      k_rowdot<<<dim3(NN/4, C), 256, 0, stream>>>(ws.Q, ws.S, ws.rs);
      // h += (rs * v3) @ grf_outw + grf_outb
      k_mgemm<128,128,true,false><<<dim3(64, 2, C), 256, 0, stream>>>(
          ws.T, PL, 0, 256, 1,
          ws.wt_gout + (long)i*2*256*256, 0, (long)256*256,
          ws.rs, NN, grf_outb + (long)i*DD,
          nullptr, nullptr, nullptr, 0, 0, ws.h, PL);

      // ===== linear attention sublayer =====
      k_ln<<<dim3(NN/4, C), 256, 0, stream>>>(ws.h, norm_g + (2*i+1)*DD, norm_b + (2*i+1)*DD, (u16*)ws.S);
      k_mgemm<128,128,false,false><<<dim3(64, 6, C), 256, 0, stream>>>(
          (const u16*)ws.S, 2L*PL, PL, 256, 1,
          ws.wt_aqkv + (long)i*2*768*256, 0, (long)768*256,
          nullptr, 0, nullptr,
          ws.Q, ws.Bp, ws.Cp, PL, 3 /* relu+1e-6 on q,k */, nullptr, 0);
      // kT = split(Bp^T) -> S ; vT = split(Cp^T) -> T
      k_transp<<<dim3(NN/64, DD/64, C), 256, 0, stream>>>(ws.Bp, (u16*)ws.S);
      k_transp<<<dim3(NN/64, DD/64, C), 256, 0, stream>>>(ws.Cp, (u16*)ws.T);
      k_ksum<<<dim3(DD, C), 256, 0, stream>>>((const u16*)ws.S, ws.ksum);
      // kv[d][e] = sum_n kT[d][n] * vT[e][n]  (split-K=8, atomic fp32)
      hipMemsetAsync(ws.kv, 0, (size_t)C*DD*DD*sizeof(float), stream);
      k_mgemm<64,64,false,false><<<dim3(4, 4, C*8), 256, 0, stream>>>(
          (const u16*)ws.S, 2L*PL, PL, NN, 8,
          (const u16*)ws.T, 2L*PL, PL,
          nullptr, 0, nullptr,
          nullptr, nullptr, nullptr, 0, 0, ws.kv, (long)DD*DD);
      // w2t[n][d] = sum_e Wout^T[n][e] * kv[d][e]
      k_mgemm<64,64,false,true><<<dim3(4, 4, C), 256, 0, stream>>>(
          ws.wt_aout + (long)i*2*256*256, 0, (long)256*256, 256, 1,
          ws.kv, (long)DD*DD, 0,
          nullptr, 0, nullptr,
          ws.w2t, nullptr, nullptr, (long)DD*DD, 0, nullptr, 0);
      k_zcalc<<<dim3(NN/4, C), 256, 0, stream>>>(ws.Q, ws.ksum, ws.rs);
      // h += (z * q) @ w2 + attn_outb
      k_mgemm<128,128,true,true><<<dim3(64, 2, C), 256, 0, stream>>>(
          ws.Q, PL, 0, 256, 1,
          ws.w2t, (long)DD*DD, 0,
          ws.rs, NN, attn_outb + (long)i*DD,
          nullptr, nullptr, nullptr, 0, 0, ws.h, PL);
    }

    k_head<<<dim3(NN/4, C), 256, 0, stream>>>(ws.h, head_w, head_b, out + (long)b0*NN*3);
  }
}

// Round 8
// 5109.739 us; speedup vs baseline: 2.7074x; 1.0540x over previous
//
#include <hip/hip_runtime.h>
#include <hip/hip_bf16.h>

#define BB 8
#define NN 8192
#define KK 6
#define DD 256
#define LL 5
#define NE (BB*NN*KK)       // 393216
#define PLANE (NN*DD)       // 2097152 elems per batch
#define INV6 (1.0f/6.000001f)

typedef unsigned short u16;
typedef __attribute__((ext_vector_type(8))) short bf8;     // 8 bf16 (4 VGPRs)
typedef __attribute__((ext_vector_type(8))) unsigned short us8;
typedef __attribute__((ext_vector_type(4))) float f32x4;

__device__ __forceinline__ float b2f(u16 u){
  union { unsigned int i; float f; } c; c.i = ((unsigned int)u) << 16; return c.f;
}
__device__ __forceinline__ u16 f2b(float f){
  union { float f; unsigned int i; } c; c.f = f;
  unsigned int x = c.i;
  x += 0x7fffu + ((x >> 16) & 1u);
  return (u16)(x >> 16);
}

// async global->LDS 16B copy: LDS dest must be wave-uniform base + lane*16
__device__ __forceinline__ void ldscp(const u16* g, u16* l){
  __builtin_amdgcn_global_load_lds(
      (const __attribute__((address_space(1))) void*)g,
      (__attribute__((address_space(3))) void*)l, 16, 0, 0);
}

// ---------------- CSR build ----------------
__global__ void k_count(const int* __restrict__ knn, int* __restrict__ off){
  int e = blockIdx.x*256 + threadIdx.x;
  if(e >= NE) return;
  int b = e / (NN*KK);
  int j = knn[e];
  atomicAdd(&off[b*(NN+1) + 1 + j], 1);
}

__global__ __launch_bounds__(1024) void k_scan(int* __restrict__ offAll){
  __shared__ int lds[1024];
  __shared__ int carry_s;
  int* off = offAll + blockIdx.x*(NN+1);
  const int len = NN+1;
  int t = threadIdx.x;
  if(t==0) carry_s = 0;
  __syncthreads();
  for(int base=0; base<len; base+=1024){
    int x = (base+t < len) ? off[base+t] : 0;
    lds[t] = x; __syncthreads();
    for(int s=1; s<1024; s<<=1){
      int v = (t>=s) ? lds[t-s] : 0;
      __syncthreads();
      lds[t] += v;
      __syncthreads();
    }
    int incl = lds[t];
    int carry = carry_s;
    __syncthreads();
    if(base+t < len) off[base+t] = incl + carry;
    if(t==1023) carry_s = carry + incl;
    __syncthreads();
  }
}

__global__ void k_fill(const int* __restrict__ knn, int* __restrict__ cursor, int* __restrict__ srcE){
  int e = blockIdx.x*256 + threadIdx.x;
  if(e >= NE) return;
  int b = e / (NN*KK);
  int n = (e % (NN*KK)) / KK;
  int j = knn[e];
  int pos = atomicAdd(&cursor[b*(NN+1) + j], 1);
  srcE[(long)b*NN*KK + pos] = n;
}

// ---- weight prep: W fp32 [L][256][N] -> Wt hi/lo bf16 [L][2][N][256] ----
__global__ __launch_bounds__(256) void k_prepw(const float* __restrict__ W, u16* __restrict__ Wt, int N){
  int n = blockIdx.x, l = blockIdx.y, k = threadIdx.x;
  float x = W[((long)l*256 + k)*N + n];
  u16 h = f2b(x);
  Wt[(((long)l*2 + 0)*N + n)*256 + k] = h;
  Wt[(((long)l*2 + 1)*N + n)*256 + k] = f2b(x - b2f(h));
}

// ---------------- embed ----------------
__global__ __launch_bounds__(256) void k_embed(const float* __restrict__ x, const float* __restrict__ ew,
                        const float* __restrict__ eb, float* __restrict__ h){
  int g = blockIdx.x, z = blockIdx.y, d = threadIdx.x;
  const float* xp = x + ((long)z*NN + g)*3;
  h[(long)z*PLANE + (long)g*DD + d] = xp[0]*ew[0*DD+d] + xp[1]*ew[1*DD+d] + xp[2]*ew[2*DD+d] + eb[d];
}

// ---------------- layernorm fp32 -> PRE-SPLIT hi/lo bf16 planes ----------------
__global__ __launch_bounds__(256) void k_ln(const float* __restrict__ h, const float* __restrict__ g,
                     const float* __restrict__ bia, u16* __restrict__ out){
  long z = blockIdx.y;
  int row = blockIdx.x*4 + (threadIdx.x >> 6);
  int lane = threadIdx.x & 63;
  const float4 x = *(const float4*)(h + z*PLANE + (long)row*DD + lane*4);
  float s  = x.x + x.y + x.z + x.w;
  float s2 = x.x*x.x + x.y*x.y + x.z*x.z + x.w*x.w;
  for(int o=1;o<64;o<<=1){ s += __shfl_xor(s,o); s2 += __shfl_xor(s2,o); }
  float m = s*(1.0f/256.0f);
  float var = s2*(1.0f/256.0f) - m*m;
  float r = rsqrtf(var + 1e-5f);
  const float4 gu = *(const float4*)(g + lane*4);
  const float4 bu = *(const float4*)(bia + lane*4);
  float v[4];
  v[0] = (x.x-m)*r*gu.x + bu.x;
  v[1] = (x.y-m)*r*gu.y + bu.y;
  v[2] = (x.z-m)*r*gu.z + bu.z;
  v[3] = (x.w-m)*r*gu.w + bu.w;
  ushort4 hv, lv;
  u16 hh;
  hh = f2b(v[0]); hv.x = hh; lv.x = f2b(v[0]-b2f(hh));
  hh = f2b(v[1]); hv.y = hh; lv.y = f2b(v[1]-b2f(hh));
  hh = f2b(v[2]); hv.z = hh; lv.z = f2b(v[2]-b2f(hh));
  hh = f2b(v[3]); hv.w = hh; lv.w = f2b(v[3]-b2f(hh));
  u16* op = out + z*2L*PLANE + (long)row*DD + lane*4;
  *(ushort4*)op = hv;
  *(ushort4*)(op + PLANE) = lv;
}

// ---------------- split-precision MFMA GEMM ----------------
// C[m][n] = sum_k A[m][k]*B[n][k]; side fp32 (split on the fly, flag true) or
// pre-split bf16 hi/lo (lo at +loOff elems; staged via global_load_lds).
// acc ≈ Ah*Bh + Al*Bh + Ah*Bl.  kSplit>1: K chunked, atomicAdd into accOut.
// Output: accOut += val; or sections o0/o1/o2. If oLoOff>0, sec0 is written as
// a split u16 pair (hi at 2*z*oStride, lo +oLoOff).
template<int BM, int BN, bool AF, bool BF>
__global__ __launch_bounds__(256) void k_mgemm(
    const void* __restrict__ Aab, long aStride, long aLoOff, int K, int kSplit,
    const void* __restrict__ Bab, long bStride, long bLoOff,
    const float* __restrict__ rowscale, long rsStride,
    const float* __restrict__ bias,
    float* __restrict__ o0, float* __restrict__ o1, float* __restrict__ o2,
    long oStride, int reluMask, long oLoOff,
    float* __restrict__ accOut, long hStride)
{
  constexpr int WM = BM/2, WN = BN/2, MT = WM/16, NT = WN/16;
  __shared__ __align__(16) u16 Ahi[BM*32];
  __shared__ __align__(16) u16 Alo[BM*32];
  __shared__ __align__(16) u16 Bhi[BN*32];
  __shared__ __align__(16) u16 Blo[BN*32];
  const int t = threadIdx.x;
  const int nz = blockIdx.z;
  const long z = nz / kSplit;
  const int chunk = nz % kSplit;
  const int kLen = K / kSplit, kLo = chunk * kLen;
  const int rowTile = blockIdx.x*BM, colTile = blockIdx.y*BN;
  const int l = t & 63, w = t >> 6;
  const int wr = w >> 1, wc = w & 1;
  const int lm = l & 15, kq = l >> 4;

  f32x4 acc[MT][NT];
  #pragma unroll
  for(int mt=0;mt<MT;mt++)
    #pragma unroll
    for(int nt=0;nt<NT;nt++) acc[mt][nt] = (f32x4){0.f,0.f,0.f,0.f};

  for(int k0=kLo; k0<kLo+kLen; k0+=32){
    __syncthreads();
    if constexpr (AF){
      constexpr int NLA = (BM*32)/(256*8);
      #pragma unroll
      for(int li=0; li<NLA; li++){
        int flat = li*256 + t;
        int row = flat>>2, kg = (flat&3)*8;
        const float* src = (const float*)Aab + z*aStride + (long)(rowTile+row)*K + k0 + kg;
        float4 v0 = ((const float4*)src)[0], v1 = ((const float4*)src)[1];
        float vs[8] = {v0.x,v0.y,v0.z,v0.w,v1.x,v1.y,v1.z,v1.w};
        us8 hv, lv;
        #pragma unroll
        for(int j=0;j<8;j++){ u16 hh = f2b(vs[j]); hv[j]=hh; lv[j]=f2b(vs[j]-b2f(hh)); }
        *(us8*)&Ahi[row*32+kg] = hv;
        *(us8*)&Alo[row*32+kg] = lv;
      }
    } else {
      constexpr int NCH = (BM*4)/256;   // 16B chunks per thread per buffer
      #pragma unroll
      for(int li=0; li<NCH; li++){
        int f = li*256 + t;
        int row = f>>2, c = (f&3)*8;
        const u16* gp = (const u16*)Aab + z*aStride + (long)(rowTile+row)*K + k0 + c;
        ldscp(gp, &Ahi[f*8]);
        ldscp(gp + aLoOff, &Alo[f*8]);
      }
    }
    if constexpr (BF){
      constexpr int NLB = (BN*32)/(256*8);
      #pragma unroll
      for(int li=0; li<NLB; li++){
        int flat = li*256 + t;
        int row = flat>>2, kg = (flat&3)*8;
        const float* src = (const float*)Bab + z*bStride + (long)(colTile+row)*K + k0 + kg;
        float4 v0 = ((const float4*)src)[0], v1 = ((const float4*)src)[1];
        float vs[8] = {v0.x,v0.y,v0.z,v0.w,v1.x,v1.y,v1.z,v1.w};
        us8 hv, lv;
        #pragma unroll
        for(int j=0;j<8;j++){ u16 hh = f2b(vs[j]); hv[j]=hh; lv[j]=f2b(vs[j]-b2f(hh)); }
        *(us8*)&Bhi[row*32+kg] = hv;
        *(us8*)&Blo[row*32+kg] = lv;
      }
    } else {
      constexpr int NCH = (BN*4)/256;
      #pragma unroll
      for(int li=0; li<NCH; li++){
        int f = li*256 + t;
        int row = f>>2, c = (f&3)*8;
        const u16* gp = (const u16*)Bab + z*bStride + (long)(colTile+row)*K + k0 + c;
        ldscp(gp, &Bhi[f*8]);
        ldscp(gp + bLoOff, &Blo[f*8]);
      }
    }
    __syncthreads();
    bf8 ah[MT], al[MT], bh[NT], bl[NT];
    #pragma unroll
    for(int mt=0;mt<MT;mt++){
      int idx = (wr*WM + mt*16 + lm)*32 + kq*8;
      ah[mt] = *(const bf8*)&Ahi[idx];
      al[mt] = *(const bf8*)&Alo[idx];
    }
    #pragma unroll
    for(int nt=0;nt<NT;nt++){
      int idx = (wc*WN + nt*16 + lm)*32 + kq*8;
      bh[nt] = *(const bf8*)&Bhi[idx];
      bl[nt] = *(const bf8*)&Blo[idx];
    }
    #pragma unroll
    for(int mt=0;mt<MT;mt++)
      #pragma unroll
      for(int nt=0;nt<NT;nt++){
        acc[mt][nt] = __builtin_amdgcn_mfma_f32_16x16x32_bf16(ah[mt], bh[nt], acc[mt][nt], 0, 0, 0);
        acc[mt][nt] = __builtin_amdgcn_mfma_f32_16x16x32_bf16(al[mt], bh[nt], acc[mt][nt], 0, 0, 0);
        acc[mt][nt] = __builtin_amdgcn_mfma_f32_16x16x32_bf16(ah[mt], bl[nt], acc[mt][nt], 0, 0, 0);
      }
  }

  // epilogue: C row = (lane>>4)*4 + reg, col = lane&15
  #pragma unroll
  for(int mt=0;mt<MT;mt++){
    #pragma unroll
    for(int r=0;r<4;r++){
      int gm = rowTile + wr*WM + mt*16 + kq*4 + r;
      float sc = rowscale ? rowscale[z*rsStride + gm] : 1.0f;
      if(accOut){
        float* hp = accOut + z*hStride + (long)gm*256;
        if(kSplit > 1){
          #pragma unroll
          for(int nt=0;nt<NT;nt++){
            int gc = colTile + wc*WN + nt*16 + lm;
            atomicAdd(&hp[gc], acc[mt][nt][r]);
          }
        } else {
          #pragma unroll
          for(int nt=0;nt<NT;nt++){
            int gc = colTile + wc*WN + nt*16 + lm;
            hp[gc] += acc[mt][nt][r]*sc + (bias ? bias[gc] : 0.f);
          }
        }
      } else {
        #pragma unroll
        for(int nt=0;nt<NT;nt++){
          int gc = colTile + wc*WN + nt*16 + lm;
          int sec = gc >> 8;
          float val = acc[mt][nt][r]*sc + (bias ? bias[gc] : 0.f);
          if((reluMask >> sec) & 1) val = fmaxf(val, 0.f) + 1e-6f;
          if(sec==0 && oLoOff){
            u16* oo = (u16*)o0 + 2*z*oStride + (long)gm*256 + (gc & 255);
            u16 hh = f2b(val);
            oo[0] = hh;
            oo[oLoOff] = f2b(val - b2f(hh));
          } else {
            float* o = (sec==0) ? o0 : ((sec==1) ? o1 : o2);
            o[z*oStride + (long)gm*256 + (gc & 255)] = val;
          }
        }
      }
    }
  }
}

// ------------- fused k+v spmm gather (fp32 in, 2-edge unroll) -------------
// MODE 0: write kout,vout fp32.  MODE 1 (final GRF hop): no kout; vout written
// as split u16 pair; rs[row] = dot(q, k3) with q reconstructed from split pair.
template<int MODE>
__global__ __launch_bounds__(256) void k_spmm2(
    const float* __restrict__ kin, const float* __restrict__ vin,
    const int* __restrict__ offB, const int* __restrict__ srcB,
    float* __restrict__ kout, void* __restrict__ vout,
    const u16* __restrict__ qpair, float* __restrict__ rs){
  long z = blockIdx.y;
  const float* kp = kin + z*PLANE;
  const float* vp = vin + z*PLANE;
  const int* off = offB + z*(NN+1);
  const int* sE  = srcB + z*(long)NN*KK;
  int row = blockIdx.x*4 + (threadIdx.x >> 6);
  int lane = threadIdx.x & 63;
  int d4 = lane*4;
  int s0 = off[row], s1 = off[row+1];
  float4 ak = {0.f,0.f,0.f,0.f};
  float4 av = {0.f,0.f,0.f,0.f};
  int e = s0;
  for(; e+1 < s1; e += 2){
    int n0 = sE[e], n1 = sE[e+1];
    float4 k0 = *(const float4*)(kp + (long)n0*DD + d4);
    float4 k1 = *(const float4*)(kp + (long)n1*DD + d4);
    float4 v0 = *(const float4*)(vp + (long)n0*DD + d4);
    float4 v1 = *(const float4*)(vp + (long)n1*DD + d4);
    ak.x += k0.x + k1.x; ak.y += k0.y + k1.y; ak.z += k0.z + k1.z; ak.w += k0.w + k1.w;
    av.x += v0.x + v1.x; av.y += v0.y + v1.y; av.z += v0.z + v1.z; av.w += v0.w + v1.w;
  }
  if(e < s1){
    int n0 = sE[e];
    float4 k0 = *(const float4*)(kp + (long)n0*DD + d4);
    float4 v0 = *(const float4*)(vp + (long)n0*DD + d4);
    ak.x += k0.x; ak.y += k0.y; ak.z += k0.z; ak.w += k0.w;
    av.x += v0.x; av.y += v0.y; av.z += v0.z; av.w += v0.w;
  }
  if constexpr (MODE == 0){
    float4 ok = {ak.x*INV6, ak.y*INV6, ak.z*INV6, ak.w*INV6};
    float4 ov = {av.x*INV6, av.y*INV6, av.z*INV6, av.w*INV6};
    *(float4*)(kout + z*PLANE + (long)row*DD + d4) = ok;
    *(float4*)((float*)vout + z*PLANE + (long)row*DD + d4) = ov;
  } else {
    // v3 split pair
    float vv[4] = {av.x*INV6, av.y*INV6, av.z*INV6, av.w*INV6};
    ushort4 hv, lv; u16 hh;
    hh = f2b(vv[0]); hv.x = hh; lv.x = f2b(vv[0]-b2f(hh));
    hh = f2b(vv[1]); hv.y = hh; lv.y = f2b(vv[1]-b2f(hh));
    hh = f2b(vv[2]); hv.z = hh; lv.z = f2b(vv[2]-b2f(hh));
    hh = f2b(vv[3]); hv.w = hh; lv.w = f2b(vv[3]-b2f(hh));
    u16* op = (u16*)vout + z*2L*PLANE + (long)row*DD + d4;
    *(ushort4*)op = hv;
    *(ushort4*)(op + PLANE) = lv;
    // rs = q . k3  (k3 = ak*INV6; factor INV6 applied after reduce)
    const u16* qp = qpair + z*2L*PLANE + (long)row*DD + d4;
    ushort4 qh = *(const ushort4*)qp;
    ushort4 ql = *(const ushort4*)(qp + PLANE);
    float q0 = b2f(qh.x)+b2f(ql.x), q1 = b2f(qh.y)+b2f(ql.y);
    float q2 = b2f(qh.z)+b2f(ql.z), q3 = b2f(qh.w)+b2f(ql.w);
    float s = q0*ak.x + q1*ak.y + q2*ak.z + q3*ak.w;
    for(int o=1;o<64;o<<=1) s += __shfl_xor(s,o);
    if(lane==0) rs[z*NN + row] = s*INV6;
  }
}

// ---------------- z = 1/(q . ksum + 1e-6), q from split pair ----------------
__global__ __launch_bounds__(256) void k_zcalc(const u16* __restrict__ qpair, const float* __restrict__ ksum,
                        float* __restrict__ rs){
  long z = blockIdx.y;
  int row = blockIdx.x*4 + (threadIdx.x >> 6);
  int lane = threadIdx.x & 63;
  const u16* qp = qpair + z*2L*PLANE + (long)row*DD + lane*4;
  ushort4 qh = *(const ushort4*)qp;
  ushort4 ql = *(const ushort4*)(qp + PLANE);
  const float4 c = *(const float4*)(ksum + z*DD + lane*4);
  float s = (b2f(qh.x)+b2f(ql.x))*c.x + (b2f(qh.y)+b2f(ql.y))*c.y
          + (b2f(qh.z)+b2f(ql.z))*c.z + (b2f(qh.w)+b2f(ql.w))*c.w;
  for(int o=1;o<64;o<<=1) s += __shfl_xor(s,o);
  if(lane==0) rs[z*NN + row] = 1.0f / (s + 1e-6f);
}

// ---- transpose fp32 [8192][256] -> pre-split hi/lo bf16 [256][8192] (+PLANE) ----
__global__ __launch_bounds__(256) void k_transp(const float* __restrict__ in, u16* __restrict__ outp){
  __shared__ float tile[64][65];
  long z = blockIdx.z;
  const float* ip = in + z*PLANE;
  u16* op = outp + z*2L*PLANE;
  int r0 = blockIdx.x*64, c0 = blockIdx.y*64;
  int t = threadIdx.x;
  {
    int r = t>>2, cg = (t&3)*16;
    #pragma unroll
    for(int j=0;j<4;j++)
      *(float4*)&tile[r][cg + j*4] = *(const float4*)(ip + (long)(r0+r)*DD + c0 + cg + j*4);
  }
  __syncthreads();
  {
    int c = t>>2, rg = t&3;
    us8 hv[2], lv[2];
    #pragma unroll
    for(int j=0;j<16;j++){
      float x = tile[rg*16+j][c];
      u16 hh = f2b(x);
      hv[j>>3][j&7] = hh;
      lv[j>>3][j&7] = f2b(x - b2f(hh));
    }
    u16* dhi = op + (long)(c0+c)*NN + r0 + rg*16;
    *(us8*)dhi = hv[0]; *(us8*)(dhi+8) = hv[1];
    u16* dlo = dhi + PLANE;
    *(us8*)dlo = lv[0]; *(us8*)(dlo+8) = lv[1];
  }
}

// ---- ksum[d] = sum_n k[n,d] from pre-split kT hi/lo ----
__global__ __launch_bounds__(256) void k_ksum(const u16* __restrict__ kT, float* __restrict__ ksum){
  long z = blockIdx.y;
  int d = blockIdx.x;
  const u16* ph = kT + z*2L*PLANE + (long)d*NN;
  const u16* pl = ph + PLANE;
  float s = 0.f;
  for(int i=threadIdx.x*4; i<NN; i+=1024){
    ushort4 a = *(const ushort4*)(ph+i);
    ushort4 b = *(const ushort4*)(pl+i);
    s += b2f(a.x)+b2f(a.y)+b2f(a.z)+b2f(a.w);
    s += b2f(b.x)+b2f(b.y)+b2f(b.z)+b2f(b.w);
  }
  for(int o=1;o<64;o<<=1) s += __shfl_xor(s,o);
  __shared__ float ws4[4];
  int w = threadIdx.x >> 6;
  if((threadIdx.x & 63)==0) ws4[w] = s;
  __syncthreads();
  if(threadIdx.x==0) ksum[z*DD + d] = ws4[0]+ws4[1]+ws4[2]+ws4[3];
}

// ---------------- head ----------------
__global__ __launch_bounds__(256) void k_head(const float* __restrict__ h, const float* __restrict__ hw,
                       const float* __restrict__ hb, float* __restrict__ out){
  long z = blockIdx.y;
  int row = blockIdx.x*4 + (threadIdx.x >> 6);
  int lane = threadIdx.x & 63;
  const float4 x = *(const float4*)(h + z*PLANE + (long)row*DD + lane*4);
  int d0 = lane*4;
  float a0 = x.x*hw[(d0+0)*3+0] + x.y*hw[(d0+1)*3+0] + x.z*hw[(d0+2)*3+0] + x.w*hw[(d0+3)*3+0];
  float a1 = x.x*hw[(d0+0)*3+1] + x.y*hw[(d0+1)*3+1] + x.z*hw[(d0+2)*3+1] + x.w*hw[(d0+3)*3+1];
  float a2 = x.x*hw[(d0+0)*3+2] + x.y*hw[(d0+1)*3+2] + x.z*hw[(d0+2)*3+2] + x.w*hw[(d0+3)*3+2];
  for(int o=1;o<64;o<<=1){
    a0 += __shfl_xor(a0,o); a1 += __shfl_xor(a1,o); a2 += __shfl_xor(a2,o);
  }
  if(lane==0){
    float* op = out + (z*NN + row)*3;
    op[0] = a0 + hb[0];
    op[1] = a1 + hb[1];
    op[2] = a2 + hb[2];
  }
}

struct Carve {
  float *h,*S,*T,*Q,*Bp,*Cp,*kv,*w2t,*ksum,*rs;
  int *off,*cursor,*srcE;
  u16 *wt_gqkv,*wt_aqkv,*wt_gout,*wt_aout;
  size_t total;
};

static Carve carve(char* base, int C){
  Carve c;
  size_t cur = 0;
  auto bump = [&](size_t bytes)->char*{
    char* p = base ? base + cur : (char*)0;
    cur += (bytes + 255) & ~(size_t)255;
    return p;
  };
  c.h    = (float*)bump((size_t)C*PLANE*4);
  c.S    = (float*)bump((size_t)C*PLANE*4);   // split u16 hi/lo (LN out, kT) OR fp32 scratch
  c.T    = (float*)bump((size_t)C*PLANE*4);   // fp32 scratch OR split vT / v3
  c.Q    = (float*)bump((size_t)C*PLANE*4);   // q split pair
  c.Bp   = (float*)bump((size_t)C*PLANE*4);   // k fp32
  c.Cp   = (float*)bump((size_t)C*PLANE*4);   // v fp32
  c.kv   = (float*)bump((size_t)C*DD*DD*4);
  c.w2t  = (float*)bump((size_t)C*DD*DD*4);   // split pair
  c.ksum = (float*)bump((size_t)C*DD*4);
  c.rs   = (float*)bump((size_t)C*NN*4);
  c.off  = (int*)bump((size_t)BB*(NN+1)*4);
  c.cursor=(int*)bump((size_t)BB*(NN+1)*4);
  c.srcE = (int*)bump((size_t)NE*4);
  c.wt_gqkv = (u16*)bump((size_t)LL*2*768*256*2);
  c.wt_aqkv = (u16*)bump((size_t)LL*2*768*256*2);
  c.wt_gout = (u16*)bump((size_t)LL*2*256*256*2);
  c.wt_aout = (u16*)bump((size_t)LL*2*256*256*2);
  c.total = cur;
  return c;
}

extern "C" void kernel_launch(void* const* d_in, const int* in_sizes, int n_in,
                              void* d_out, int out_size, void* d_ws, size_t ws_size,
                              hipStream_t stream)
{
  const float* x        = (const float*)d_in[0];
  const int*   knn      = (const int*)d_in[1];
  const float* emb_w    = (const float*)d_in[2];
  const float* emb_b    = (const float*)d_in[3];
  const float* norm_g   = (const float*)d_in[4];
  const float* norm_b   = (const float*)d_in[5];
  const float* grf_qkv  = (const float*)d_in[6];
  const float* grf_outw = (const float*)d_in[7];
  const float* grf_outb = (const float*)d_in[8];
  const float* attn_qkv = (const float*)d_in[9];
  const float* attn_outw= (const float*)d_in[10];
  const float* attn_outb= (const float*)d_in[11];
  const float* head_w   = (const float*)d_in[12];
  const float* head_b   = (const float*)d_in[13];
  float* out = (float*)d_out;

  int C = 1;
  for(int cc=BB; cc>=1; cc>>=1){ if(carve(nullptr, cc).total <= ws_size){ C = cc; break; } }
  Carve ws = carve((char*)d_ws, C);

  // ---- weight prep (hi/lo bf16, transposed to [N][K]) ----
  k_prepw<<<dim3(768, LL), 256, 0, stream>>>(grf_qkv,  ws.wt_gqkv, 768);
  k_prepw<<<dim3(768, LL), 256, 0, stream>>>(attn_qkv, ws.wt_aqkv, 768);
  k_prepw<<<dim3(256, LL), 256, 0, stream>>>(grf_outw, ws.wt_gout, 256);
  k_prepw<<<dim3(256, LL), 256, 0, stream>>>(attn_outw,ws.wt_aout, 256);

  // ---- CSR build for all batches ----
  hipMemsetAsync(ws.off, 0, (size_t)BB*(NN+1)*sizeof(int), stream);
  k_count<<<dim3((NE+255)/256), 256, 0, stream>>>(knn, ws.off);
  k_scan<<<dim3(BB), 1024, 0, stream>>>(ws.off);
  hipMemcpyAsync(ws.cursor, ws.off, (size_t)BB*(NN+1)*sizeof(int), hipMemcpyDeviceToDevice, stream);
  k_fill<<<dim3((NE+255)/256), 256, 0, stream>>>(knn, ws.cursor, ws.srcE);

  const long PL = PLANE;
  for(int b0=0; b0<BB; b0+=C){
    const int* offB  = ws.off  + (long)b0*(NN+1);
    const int* srcB  = ws.srcE + (long)b0*NN*KK;

    k_embed<<<dim3(NN, C), 256, 0, stream>>>(x + (long)b0*NN*3, emb_w, emb_b, ws.h);

    for(int i=0; i<LL; i++){
      // ===== GRF sublayer =====
      k_ln<<<dim3(NN/4, C), 256, 0, stream>>>(ws.h, norm_g + (2*i)*DD, norm_b + (2*i)*DD, (u16*)ws.S);
      k_mgemm<128,128,false,false><<<dim3(64, 6, C), 256, 0, stream>>>(
          (const u16*)ws.S, 2L*PL, PL, 256, 1,
          ws.wt_gqkv + (long)i*2*768*256, 0, (long)768*256,
          nullptr, 0, nullptr,
          ws.Q, ws.Bp, ws.Cp, PL, 0, PL /* q split */, nullptr, 0);
      // hops: (Bp,Cp)->(S,T)->(Bp,Cp)->final: v3 split into T + fused rowdot
      k_spmm2<0><<<dim3(NN/4, C), 256, 0, stream>>>(ws.Bp, ws.Cp, offB, srcB, ws.S, ws.T, nullptr, nullptr);
      k_spmm2<0><<<dim3(NN/4, C), 256, 0, stream>>>(ws.S,  ws.T,  offB, srcB, ws.Bp, ws.Cp, nullptr, nullptr);
      k_spmm2<1><<<dim3(NN/4, C), 256, 0, stream>>>(ws.Bp, ws.Cp, offB, srcB, nullptr, ws.T, (const u16*)ws.Q, ws.rs);
      // h += (rs * v3) @ grf_outw + grf_outb
      k_mgemm<128,128,false,false><<<dim3(64, 2, C), 256, 0, stream>>>(
          (const u16*)ws.T, 2L*PL, PL, 256, 1,
          ws.wt_gout + (long)i*2*256*256, 0, (long)256*256,
          ws.rs, NN, grf_outb + (long)i*DD,
          nullptr, nullptr, nullptr, 0, 0, 0, ws.h, PL);

      // ===== linear attention sublayer =====
      k_ln<<<dim3(NN/4, C), 256, 0, stream>>>(ws.h, norm_g + (2*i+1)*DD, norm_b + (2*i+1)*DD, (u16*)ws.S);
      k_mgemm<128,128,false,false><<<dim3(64, 6, C), 256, 0, stream>>>(
          (const u16*)ws.S, 2L*PL, PL, 256, 1,
          ws.wt_aqkv + (long)i*2*768*256, 0, (long)768*256,
          nullptr, 0, nullptr,
          ws.Q, ws.Bp, ws.Cp, PL, 3 /* relu q,k */, PL /* q split */, nullptr, 0);
      // kT = split(Bp^T) -> S ; vT = split(Cp^T) -> T
      k_transp<<<dim3(NN/64, DD/64, C), 256, 0, stream>>>(ws.Bp, (u16*)ws.S);
      k_transp<<<dim3(NN/64, DD/64, C), 256, 0, stream>>>(ws.Cp, (u16*)ws.T);
      k_ksum<<<dim3(DD, C), 256, 0, stream>>>((const u16*)ws.S, ws.ksum);
      // kv[d][e] = sum_n kT[d][n] * vT[e][n]  (split-K=8, atomic fp32)
      hipMemsetAsync(ws.kv, 0, (size_t)C*DD*DD*sizeof(float), stream);
      k_mgemm<64,64,false,false><<<dim3(4, 4, C*8), 256, 0, stream>>>(
          (const u16*)ws.S, 2L*PL, PL, NN, 8,
          (const u16*)ws.T, 2L*PL, PL,
          nullptr, 0, nullptr,
          nullptr, nullptr, nullptr, 0, 0, 0, ws.kv, (long)DD*DD);
      // w2t[n][d] = sum_e Wout^T[n][e] * kv[d][e]  -> split pair
      k_mgemm<64,64,false,true><<<dim3(4, 4, C), 256, 0, stream>>>(
          ws.wt_aout + (long)i*2*256*256, 0, (long)256*256, 256, 1,
          ws.kv, (long)DD*DD, 0,
          nullptr, 0, nullptr,
          ws.w2t, nullptr, nullptr, (long)DD*DD, 0, (long)DD*DD /* split out */,
          nullptr, 0);
      k_zcalc<<<dim3(NN/4, C), 256, 0, stream>>>((const u16*)ws.Q, ws.ksum, ws.rs);
      // h += (z * q) @ w2 + attn_outb
      k_mgemm<128,128,false,false><<<dim3(64, 2, C), 256, 0, stream>>>(
          (const u16*)ws.Q, 2L*PL, PL, 256, 1,
          (const u16*)ws.w2t, 2L*DD*DD, (long)DD*DD,
          ws.rs, NN, attn_outb + (long)i*DD,
          nullptr, nullptr, nullptr, 0, 0, 0, ws.h, PL);
    }

    k_head<<<dim3(NN/4, C), 256, 0, stream>>>(ws.h, head_w, head_b, out + (long)b0*NN*3);
  }
}

// Round 9
// 3341.233 us; speedup vs baseline: 4.1404x; 1.5293x over previous
//
#include <hip/hip_runtime.h>

#define BB 8
#define NN 8192
#define KK 6
#define DD 256
#define LL 5
#define NE (BB*NN*KK)       // 393216
#define PLANE (NN*DD)       // 2097152 elems per batch
#define INV6 (1.0f/6.000001f)

typedef unsigned short u16;
typedef __attribute__((ext_vector_type(8))) _Float16 h8;
typedef __attribute__((ext_vector_type(8))) unsigned short us8;
typedef __attribute__((ext_vector_type(4))) float f32x4;

__device__ __forceinline__ u16 f2h(float f){
  union { _Float16 h; u16 u; } c; c.h = (_Float16)f; return c.u;
}
__device__ __forceinline__ float h2f(u16 u){
  union { _Float16 h; u16 u; } c; c.u = u; return (float)c.h;
}

// async global->LDS 16B copy: LDS dest must be wave-uniform base + lane*16
__device__ __forceinline__ void ldscp(const u16* g, u16* l){
  __builtin_amdgcn_global_load_lds(
      (const __attribute__((address_space(1))) void*)g,
      (__attribute__((address_space(3))) void*)l, 16, 0, 0);
}

// ---------------- CSR build ----------------
__global__ void k_count(const int* __restrict__ knn, int* __restrict__ off){
  int e = blockIdx.x*256 + threadIdx.x;
  if(e >= NE) return;
  int b = e / (NN*KK);
  int j = knn[e];
  atomicAdd(&off[b*(NN+1) + 1 + j], 1);
}

__global__ __launch_bounds__(1024) void k_scan(int* __restrict__ offAll){
  __shared__ int lds[1024];
  __shared__ int carry_s;
  int* off = offAll + blockIdx.x*(NN+1);
  const int len = NN+1;
  int t = threadIdx.x;
  if(t==0) carry_s = 0;
  __syncthreads();
  for(int base=0; base<len; base+=1024){
    int x = (base+t < len) ? off[base+t] : 0;
    lds[t] = x; __syncthreads();
    for(int s=1; s<1024; s<<=1){
      int v = (t>=s) ? lds[t-s] : 0;
      __syncthreads();
      lds[t] += v;
      __syncthreads();
    }
    int incl = lds[t];
    int carry = carry_s;
    __syncthreads();
    if(base+t < len) off[base+t] = incl + carry;
    if(t==1023) carry_s = carry + incl;
    __syncthreads();
  }
}

__global__ void k_fill(const int* __restrict__ knn, int* __restrict__ cursor, int* __restrict__ srcE){
  int e = blockIdx.x*256 + threadIdx.x;
  if(e >= NE) return;
  int b = e / (NN*KK);
  int n = (e % (NN*KK)) / KK;
  int j = knn[e];
  int pos = atomicAdd(&cursor[b*(NN+1) + j], 1);
  srcE[(long)b*NN*KK + pos] = n;
}

// ---- weight prep: W fp32 [L][256][N] -> Wt hi/lo fp16 [L][2][N][256] ----
__global__ __launch_bounds__(256) void k_prepw(const float* __restrict__ W, u16* __restrict__ Wt, int N){
  int n = blockIdx.x, l = blockIdx.y, k = threadIdx.x;
  float x = W[((long)l*256 + k)*N + n];
  u16 hb = f2h(x);
  Wt[(((long)l*2 + 0)*N + n)*256 + k] = hb;
  Wt[(((long)l*2 + 1)*N + n)*256 + k] = f2h(x - h2f(hb));
}

// ---------------- embed ----------------
__global__ __launch_bounds__(256) void k_embed(const float* __restrict__ x, const float* __restrict__ ew,
                        const float* __restrict__ eb, float* __restrict__ h){
  int g = blockIdx.x, z = blockIdx.y, d = threadIdx.x;
  const float* xp = x + ((long)z*NN + g)*3;
  h[(long)z*PLANE + (long)g*DD + d] = xp[0]*ew[0*DD+d] + xp[1]*ew[1*DD+d] + xp[2]*ew[2*DD+d] + eb[d];
}

// ---------------- layernorm fp32 -> fp16 single plane ----------------
__global__ __launch_bounds__(256) void k_ln(const float* __restrict__ h, const float* __restrict__ g,
                     const float* __restrict__ bia, u16* __restrict__ out){
  long z = blockIdx.y;
  int row = blockIdx.x*4 + (threadIdx.x >> 6);
  int lane = threadIdx.x & 63;
  const float4 x = *(const float4*)(h + z*PLANE + (long)row*DD + lane*4);
  float s  = x.x + x.y + x.z + x.w;
  float s2 = x.x*x.x + x.y*x.y + x.z*x.z + x.w*x.w;
  for(int o=1;o<64;o<<=1){ s += __shfl_xor(s,o); s2 += __shfl_xor(s2,o); }
  float m = s*(1.0f/256.0f);
  float var = s2*(1.0f/256.0f) - m*m;
  float r = rsqrtf(var + 1e-5f);
  const float4 gu = *(const float4*)(g + lane*4);
  const float4 bu = *(const float4*)(bia + lane*4);
  ushort4 o4;
  o4.x = f2h((x.x-m)*r*gu.x + bu.x);
  o4.y = f2h((x.y-m)*r*gu.y + bu.y);
  o4.z = f2h((x.z-m)*r*gu.z + bu.z);
  o4.w = f2h((x.w-m)*r*gu.w + bu.w);
  *(ushort4*)(out + z*PLANE + (long)row*DD + lane*4) = o4;
}

// ---------------- fp16 MFMA GEMM ----------------
// C[m][n] = sum_k A[m][k]*B[n][k]. A: fp16 single (u16 bits), staged ldscp;
// optional ASPLIT: lo plane at +aLoOff. B: fp16 (BSPLIT: hi/lo at +bLoOff) or
// fp32 converted on the fly (BF32). MFMAs: A*Bh [+A*Bl if BSPLIT] [+Al*Bh if ASPLIT].
// kSplit>1: K chunked over z, fp32 atomicAdd into accOut (no scale/bias).
// Else epilogue: val = acc*rowscale[m] + bias[n]; accOut+= or fp16 sections
// o0/o1/o2 (sec=gc>>8), relu+1e-6 per reluMask bit; oLoOff>0: sec0 as split pair.
template<int BM,int BN,bool ASPLIT,bool BF32,bool BSPLIT>
__global__ __launch_bounds__(256) void k_mgemm(
    const u16* __restrict__ A, long aStride, long aLoOff, int K, int kSplit,
    const void* __restrict__ Bv, long bStride, long bLoOff,
    const float* __restrict__ rowscale, long rsStride,
    const float* __restrict__ bias,
    u16* __restrict__ o0, u16* __restrict__ o1, u16* __restrict__ o2,
    long oStride, int reluMask, long oLoOff,
    float* __restrict__ accOut, long hStride)
{
  constexpr int WM = BM/2, WN = BN/2, MT = WM/16, NT = WN/16;
  __shared__ __align__(16) u16 Ahi[BM*32];
  __shared__ __align__(16) u16 Alo[ASPLIT ? BM*32 : 8];
  __shared__ __align__(16) u16 Bhi[BN*32];
  __shared__ __align__(16) u16 Blo[BSPLIT ? BN*32 : 8];
  const int t = threadIdx.x;
  const int nz = blockIdx.z;
  const long z = nz / kSplit;
  const int chunk = nz % kSplit;
  const int kLen = K / kSplit, kLo = chunk * kLen;
  const int rowTile = blockIdx.x*BM, colTile = blockIdx.y*BN;
  const int l = t & 63, w = t >> 6;
  const int wr = w >> 1, wc = w & 1;
  const int lm = l & 15, kq = l >> 4;

  f32x4 acc[MT][NT];
  #pragma unroll
  for(int mt=0;mt<MT;mt++)
    #pragma unroll
    for(int nt=0;nt<NT;nt++) acc[mt][nt] = (f32x4){0.f,0.f,0.f,0.f};

  for(int k0=kLo; k0<kLo+kLen; k0+=32){
    __syncthreads();
    {
      constexpr int NCH = BM/64;
      #pragma unroll
      for(int li=0; li<NCH; li++){
        int f = li*256 + t;
        int row = f>>2, c = (f&3)*8;
        const u16* gp = A + z*aStride + (long)(rowTile+row)*K + k0 + c;
        ldscp(gp, &Ahi[f*8]);
        if constexpr (ASPLIT) ldscp(gp + aLoOff, &Alo[f*8]);
      }
    }
    if constexpr (BF32){
      constexpr int NCH = BN/64;
      #pragma unroll
      for(int li=0; li<NCH; li++){
        int f = li*256 + t;
        int row = f>>2, c = (f&3)*8;
        const float* src = (const float*)Bv + z*bStride + (long)(colTile+row)*K + k0 + c;
        float4 v0 = ((const float4*)src)[0], v1 = ((const float4*)src)[1];
        us8 hv;
        hv[0]=f2h(v0.x); hv[1]=f2h(v0.y); hv[2]=f2h(v0.z); hv[3]=f2h(v0.w);
        hv[4]=f2h(v1.x); hv[5]=f2h(v1.y); hv[6]=f2h(v1.z); hv[7]=f2h(v1.w);
        *(us8*)&Bhi[f*8] = hv;
      }
    } else {
      constexpr int NCH = BN/64;
      #pragma unroll
      for(int li=0; li<NCH; li++){
        int f = li*256 + t;
        int row = f>>2, c = (f&3)*8;
        const u16* gp = (const u16*)Bv + z*bStride + (long)(colTile+row)*K + k0 + c;
        ldscp(gp, &Bhi[f*8]);
        if constexpr (BSPLIT) ldscp(gp + bLoOff, &Blo[f*8]);
      }
    }
    __syncthreads();
    h8 ah[MT], al[MT], bh[NT], bl[NT];
    #pragma unroll
    for(int mt=0;mt<MT;mt++){
      int idx = (wr*WM + mt*16 + lm)*32 + kq*8;
      ah[mt] = *(const h8*)&Ahi[idx];
      if constexpr (ASPLIT) al[mt] = *(const h8*)&Alo[idx];
    }
    #pragma unroll
    for(int nt=0;nt<NT;nt++){
      int idx = (wc*WN + nt*16 + lm)*32 + kq*8;
      bh[nt] = *(const h8*)&Bhi[idx];
      if constexpr (BSPLIT) bl[nt] = *(const h8*)&Blo[idx];
    }
    #pragma unroll
    for(int mt=0;mt<MT;mt++)
      #pragma unroll
      for(int nt=0;nt<NT;nt++){
        acc[mt][nt] = __builtin_amdgcn_mfma_f32_16x16x32_f16(ah[mt], bh[nt], acc[mt][nt], 0, 0, 0);
        if constexpr (BSPLIT)
          acc[mt][nt] = __builtin_amdgcn_mfma_f32_16x16x32_f16(ah[mt], bl[nt], acc[mt][nt], 0, 0, 0);
        if constexpr (ASPLIT)
          acc[mt][nt] = __builtin_amdgcn_mfma_f32_16x16x32_f16(al[mt], bh[nt], acc[mt][nt], 0, 0, 0);
      }
  }

  // epilogue: C row = (lane>>4)*4 + reg, col = lane&15
  #pragma unroll
  for(int mt=0;mt<MT;mt++){
    #pragma unroll
    for(int r=0;r<4;r++){
      int gm = rowTile + wr*WM + mt*16 + kq*4 + r;
      float sc = rowscale ? rowscale[z*rsStride + gm] : 1.0f;
      if(accOut){
        float* hp = accOut + z*hStride + (long)gm*256;
        if(kSplit > 1){
          #pragma unroll
          for(int nt=0;nt<NT;nt++){
            int gc = colTile + wc*WN + nt*16 + lm;
            atomicAdd(&hp[gc], acc[mt][nt][r]);
          }
        } else {
          #pragma unroll
          for(int nt=0;nt<NT;nt++){
            int gc = colTile + wc*WN + nt*16 + lm;
            hp[gc] += acc[mt][nt][r]*sc + (bias ? bias[gc] : 0.f);
          }
        }
      } else {
        #pragma unroll
        for(int nt=0;nt<NT;nt++){
          int gc = colTile + wc*WN + nt*16 + lm;
          int sec = gc >> 8;
          u16* o = (sec==0) ? o0 : ((sec==1) ? o1 : o2);
          float val = acc[mt][nt][r]*sc + (bias ? bias[gc] : 0.f);
          if((reluMask >> sec) & 1) val = fmaxf(val, 0.f) + 1e-6f;
          if(sec==0 && oLoOff){
            u16* oo = o0 + 2*z*oStride + (long)gm*256 + (gc & 255);
            u16 hb = f2h(val);
            oo[0] = hb;
            oo[oLoOff] = f2h(val - h2f(hb));
          } else {
            o[z*oStride + (long)gm*256 + (gc & 255)] = f2h(val);
          }
        }
      }
    }
  }
}

// ------------- fused k+v spmm gather (fp16 planes, fp32 accum) -------------
// One 32-lane half-wave per row (8 halves = 16B per lane), 2-edge unroll.
// MODE 0: write kout,vout fp16. MODE 1: no kout; vout = v3 fp16;
// rs[row] = dot(q, k3) with q fp16.
template<int MODE>
__global__ __launch_bounds__(256) void k_spmm2(
    const u16* __restrict__ kin, const u16* __restrict__ vin,
    const int* __restrict__ offB, const int* __restrict__ srcB,
    u16* __restrict__ kout, u16* __restrict__ vout,
    const u16* __restrict__ q, float* __restrict__ rs){
  long z = blockIdx.y;
  const u16* kp = kin + z*PLANE;
  const u16* vp = vin + z*PLANE;
  const int* off = offB + z*(NN+1);
  const int* sE  = srcB + z*(long)NN*KK;
  int row = blockIdx.x*8 + (threadIdx.x >> 5);
  int l32 = threadIdx.x & 31;
  int d8 = l32*8;
  int s0 = off[row], s1 = off[row+1];
  float ak[8], av[8];
  #pragma unroll
  for(int j=0;j<8;j++){ ak[j]=0.f; av[j]=0.f; }
  int e = s0;
  for(; e+1 < s1; e += 2){
    int n0 = sE[e], n1 = sE[e+1];
    us8 k0 = *(const us8*)(kp + (long)n0*DD + d8);
    us8 k1 = *(const us8*)(kp + (long)n1*DD + d8);
    us8 v0 = *(const us8*)(vp + (long)n0*DD + d8);
    us8 v1 = *(const us8*)(vp + (long)n1*DD + d8);
    #pragma unroll
    for(int j=0;j<8;j++){
      ak[j] += h2f(k0[j]) + h2f(k1[j]);
      av[j] += h2f(v0[j]) + h2f(v1[j]);
    }
  }
  if(e < s1){
    int n0 = sE[e];
    us8 k0 = *(const us8*)(kp + (long)n0*DD + d8);
    us8 v0 = *(const us8*)(vp + (long)n0*DD + d8);
    #pragma unroll
    for(int j=0;j<8;j++){ ak[j] += h2f(k0[j]); av[j] += h2f(v0[j]); }
  }
  if constexpr (MODE == 0){
    us8 ok, ov;
    #pragma unroll
    for(int j=0;j<8;j++){ ok[j] = f2h(ak[j]*INV6); ov[j] = f2h(av[j]*INV6); }
    *(us8*)(kout + z*PLANE + (long)row*DD + d8) = ok;
    *(us8*)(vout + z*PLANE + (long)row*DD + d8) = ov;
  } else {
    us8 ov;
    #pragma unroll
    for(int j=0;j<8;j++) ov[j] = f2h(av[j]*INV6);
    *(us8*)(vout + z*PLANE + (long)row*DD + d8) = ov;
    us8 qv = *(const us8*)(q + z*PLANE + (long)row*DD + d8);
    float s = 0.f;
    #pragma unroll
    for(int j=0;j<8;j++) s += h2f(qv[j]) * ak[j];
    for(int o=1;o<32;o<<=1) s += __shfl_xor(s,o);
    if(l32==0) rs[z*NN + row] = s*INV6;
  }
}

// ---------------- z = 1/(q . ksum + 1e-6), q fp16 ----------------
__global__ __launch_bounds__(256) void k_zcalc(const u16* __restrict__ q, const float* __restrict__ ksum,
                        float* __restrict__ rs){
  long z = blockIdx.y;
  int row = blockIdx.x*4 + (threadIdx.x >> 6);
  int lane = threadIdx.x & 63;
  ushort4 qv = *(const ushort4*)(q + z*PLANE + (long)row*DD + lane*4);
  const float4 c = *(const float4*)(ksum + z*DD + lane*4);
  float s = h2f(qv.x)*c.x + h2f(qv.y)*c.y + h2f(qv.z)*c.z + h2f(qv.w)*c.w;
  for(int o=1;o<64;o<<=1) s += __shfl_xor(s,o);
  if(lane==0) rs[z*NN + row] = 1.0f / (s + 1e-6f);
}

// ---- transpose fp16 [8192][256] -> fp16 [256][8192] ----
__global__ __launch_bounds__(256) void k_transp(const u16* __restrict__ in, u16* __restrict__ outp){
  __shared__ u16 tile[64][72];
  long z = blockIdx.z;
  const u16* ip = in + z*PLANE;
  u16* op = outp + z*PLANE;
  int r0 = blockIdx.x*64, c0 = blockIdx.y*64;
  int t = threadIdx.x;
  {
    int r = t>>2, cg = (t&3)*16;
    *(us8*)&tile[r][cg]   = *(const us8*)(ip + (long)(r0+r)*DD + c0 + cg);
    *(us8*)&tile[r][cg+8] = *(const us8*)(ip + (long)(r0+r)*DD + c0 + cg + 8);
  }
  __syncthreads();
  {
    int c = t>>2, rg = t&3;
    us8 a, b;
    #pragma unroll
    for(int j=0;j<8;j++){ a[j] = tile[rg*16+j][c]; b[j] = tile[rg*16+8+j][c]; }
    u16* dst = op + (long)(c0+c)*NN + r0 + rg*16;
    *(us8*)dst = a; *(us8*)(dst+8) = b;
  }
}

// ---- ksum[d] = sum_n kT[d][n], kT fp16 [256][8192] ----
__global__ __launch_bounds__(256) void k_ksum(const u16* __restrict__ kT, float* __restrict__ ksum){
  long z = blockIdx.y;
  int d = blockIdx.x;
  const u16* p = kT + z*PLANE + (long)d*NN;
  float s = 0.f;
  for(int i=threadIdx.x*8; i<NN; i+=2048){
    us8 a = *(const us8*)(p+i);
    #pragma unroll
    for(int j=0;j<8;j++) s += h2f(a[j]);
  }
  for(int o=1;o<64;o<<=1) s += __shfl_xor(s,o);
  __shared__ float ws4[4];
  int w = threadIdx.x >> 6;
  if((threadIdx.x & 63)==0) ws4[w] = s;
  __syncthreads();
  if(threadIdx.x==0) ksum[z*DD + d] = ws4[0]+ws4[1]+ws4[2]+ws4[3];
}

// ---------------- head ----------------
__global__ __launch_bounds__(256) void k_head(const float* __restrict__ h, const float* __restrict__ hw,
                       const float* __restrict__ hb, float* __restrict__ out){
  long z = blockIdx.y;
  int row = blockIdx.x*4 + (threadIdx.x >> 6);
  int lane = threadIdx.x & 63;
  const float4 x = *(const float4*)(h + z*PLANE + (long)row*DD + lane*4);
  int d0 = lane*4;
  float a0 = x.x*hw[(d0+0)*3+0] + x.y*hw[(d0+1)*3+0] + x.z*hw[(d0+2)*3+0] + x.w*hw[(d0+3)*3+0];
  float a1 = x.x*hw[(d0+0)*3+1] + x.y*hw[(d0+1)*3+1] + x.z*hw[(d0+2)*3+1] + x.w*hw[(d0+3)*3+1];
  float a2 = x.x*hw[(d0+0)*3+2] + x.y*hw[(d0+1)*3+2] + x.z*hw[(d0+2)*3+2] + x.w*hw[(d0+3)*3+2];
  for(int o=1;o<64;o<<=1){
    a0 += __shfl_xor(a0,o); a1 += __shfl_xor(a1,o); a2 += __shfl_xor(a2,o);
  }
  if(lane==0){
    float* op = out + (z*NN + row)*3;
    op[0] = a0 + hb[0];
    op[1] = a1 + hb[1];
    op[2] = a2 + hb[2];
  }
}

struct Carve {
  float *h; u16 *L,*Q,*Bp,*Cp,*T;
  float *kvf; u16 *w2t;
  float *ksum,*rs;
  int *off,*cursor,*srcE;
  u16 *wt_gqkv,*wt_aqkv,*wt_gout,*wt_aout;
  size_t total;
};

static Carve carve(char* base, int C){
  Carve c;
  size_t cur = 0;
  auto bump = [&](size_t bytes)->char*{
    char* p = base ? base + cur : (char*)0;
    cur += (bytes + 255) & ~(size_t)255;
    return p;
  };
  c.h    = (float*)bump((size_t)C*PLANE*4);
  c.L    = (u16*)bump((size_t)C*PLANE*2);   // LN out / kT / k-hop pong
  c.Q    = (u16*)bump((size_t)C*PLANE*2);
  c.Bp   = (u16*)bump((size_t)C*PLANE*2);   // k
  c.Cp   = (u16*)bump((size_t)C*PLANE*2);   // v
  c.T    = (u16*)bump((size_t)C*PLANE*2);   // v-hop pong / v3 / vT
  c.kvf  = (float*)bump((size_t)C*DD*DD*4);
  c.w2t  = (u16*)bump((size_t)C*2*DD*DD*2); // split pair
  c.ksum = (float*)bump((size_t)C*DD*4);
  c.rs   = (float*)bump((size_t)C*NN*4);
  c.off  = (int*)bump((size_t)BB*(NN+1)*4);
  c.cursor=(int*)bump((size_t)BB*(NN+1)*4);
  c.srcE = (int*)bump((size_t)NE*4);
  c.wt_gqkv = (u16*)bump((size_t)LL*2*768*256*2);
  c.wt_aqkv = (u16*)bump((size_t)LL*2*768*256*2);
  c.wt_gout = (u16*)bump((size_t)LL*2*256*256*2);
  c.wt_aout = (u16*)bump((size_t)LL*2*256*256*2);
  c.total = cur;
  return c;
}

extern "C" void kernel_launch(void* const* d_in, const int* in_sizes, int n_in,
                              void* d_out, int out_size, void* d_ws, size_t ws_size,
                              hipStream_t stream)
{
  const float* x        = (const float*)d_in[0];
  const int*   knn      = (const int*)d_in[1];
  const float* emb_w    = (const float*)d_in[2];
  const float* emb_b    = (const float*)d_in[3];
  const float* norm_g   = (const float*)d_in[4];
  const float* norm_b   = (const float*)d_in[5];
  const float* grf_qkv  = (const float*)d_in[6];
  const float* grf_outw = (const float*)d_in[7];
  const float* grf_outb = (const float*)d_in[8];
  const float* attn_qkv = (const float*)d_in[9];
  const float* attn_outw= (const float*)d_in[10];
  const float* attn_outb= (const float*)d_in[11];
  const float* head_w   = (const float*)d_in[12];
  const float* head_b   = (const float*)d_in[13];
  float* out = (float*)d_out;

  int C = 1;
  for(int cc=BB; cc>=1; cc>>=1){ if(carve(nullptr, cc).total <= ws_size){ C = cc; break; } }
  Carve ws = carve((char*)d_ws, C);

  // ---- weight prep (hi/lo fp16, transposed to [N][K]) ----
  k_prepw<<<dim3(768, LL), 256, 0, stream>>>(grf_qkv,  ws.wt_gqkv, 768);
  k_prepw<<<dim3(768, LL), 256, 0, stream>>>(attn_qkv, ws.wt_aqkv, 768);
  k_prepw<<<dim3(256, LL), 256, 0, stream>>>(grf_outw, ws.wt_gout, 256);
  k_prepw<<<dim3(256, LL), 256, 0, stream>>>(attn_outw,ws.wt_aout, 256);

  // ---- CSR build for all batches ----
  hipMemsetAsync(ws.off, 0, (size_t)BB*(NN+1)*sizeof(int), stream);
  k_count<<<dim3((NE+255)/256), 256, 0, stream>>>(knn, ws.off);
  k_scan<<<dim3(BB), 1024, 0, stream>>>(ws.off);
  hipMemcpyAsync(ws.cursor, ws.off, (size_t)BB*(NN+1)*sizeof(int), hipMemcpyDeviceToDevice, stream);
  k_fill<<<dim3((NE+255)/256), 256, 0, stream>>>(knn, ws.cursor, ws.srcE);

  const long PL = PLANE;
  for(int b0=0; b0<BB; b0+=C){
    const int* offB  = ws.off  + (long)b0*(NN+1);
    const int* srcB  = ws.srcE + (long)b0*NN*KK;

    k_embed<<<dim3(NN, C), 256, 0, stream>>>(x + (long)b0*NN*3, emb_w, emb_b, ws.h);

    for(int i=0; i<LL; i++){
      // ===== GRF sublayer =====
      k_ln<<<dim3(NN/4, C), 256, 0, stream>>>(ws.h, norm_g + (2*i)*DD, norm_b + (2*i)*DD, ws.L);
      k_mgemm<128,128,false,false,true><<<dim3(64, 6, C), 256, 0, stream>>>(
          ws.L, PL, 0, 256, 1,
          ws.wt_gqkv + (long)i*2*768*256, 0, (long)768*256,
          nullptr, 0, nullptr,
          ws.Q, ws.Bp, ws.Cp, PL, 0, 0, nullptr, 0);
      // hops: (Bp,Cp)->(L,T)->(Bp,Cp)-> final: v3 into T + fused rowdot
      k_spmm2<0><<<dim3(NN/8, C), 256, 0, stream>>>(ws.Bp, ws.Cp, offB, srcB, ws.L, ws.T, nullptr, nullptr);
      k_spmm2<0><<<dim3(NN/8, C), 256, 0, stream>>>(ws.L,  ws.T,  offB, srcB, ws.Bp, ws.Cp, nullptr, nullptr);
      k_spmm2<1><<<dim3(NN/8, C), 256, 0, stream>>>(ws.Bp, ws.Cp, offB, srcB, nullptr, ws.T, ws.Q, ws.rs);
      // h += (rs * v3) @ grf_outw + grf_outb
      k_mgemm<128,128,false,false,true><<<dim3(64, 2, C), 256, 0, stream>>>(
          ws.T, PL, 0, 256, 1,
          ws.wt_gout + (long)i*2*256*256, 0, (long)256*256,
          ws.rs, NN, grf_outb + (long)i*DD,
          nullptr, nullptr, nullptr, 0, 0, 0, ws.h, PL);

      // ===== linear attention sublayer =====
      k_ln<<<dim3(NN/4, C), 256, 0, stream>>>(ws.h, norm_g + (2*i+1)*DD, norm_b + (2*i+1)*DD, ws.L);
      k_mgemm<128,128,false,false,true><<<dim3(64, 6, C), 256, 0, stream>>>(
          ws.L, PL, 0, 256, 1,
          ws.wt_aqkv + (long)i*2*768*256, 0, (long)768*256,
          nullptr, 0, nullptr,
          ws.Q, ws.Bp, ws.Cp, PL, 3 /* relu+1e-6 on q,k */, 0, nullptr, 0);
      // kT = Bp^T -> L (LN out dead); vT = Cp^T -> T
      k_transp<<<dim3(NN/64, DD/64, C), 256, 0, stream>>>(ws.Bp, ws.L);
      k_transp<<<dim3(NN/64, DD/64, C), 256, 0, stream>>>(ws.Cp, ws.T);
      k_ksum<<<dim3(DD, C), 256, 0, stream>>>(ws.L, ws.ksum);
      // kv[d][e] = sum_n kT[d][n] * vT[e][n]  (split-K=8, atomic fp32)
      hipMemsetAsync(ws.kvf, 0, (size_t)C*DD*DD*sizeof(float), stream);
      k_mgemm<64,64,false,false,false><<<dim3(4, 4, C*8), 256, 0, stream>>>(
          ws.L, PL, 0, NN, 8,
          ws.T, PL, 0,
          nullptr, 0, nullptr,
          nullptr, nullptr, nullptr, 0, 0, 0, ws.kvf, (long)DD*DD);
      // w2t[n][d] = sum_e WoutT[n][e](split) * kv[d][e]  -> split fp16 pair
      k_mgemm<64,64,true,true,false><<<dim3(4, 4, C), 256, 0, stream>>>(
          ws.wt_aout + (long)i*2*256*256, 0, (long)256*256, 256, 1,
          ws.kvf, (long)DD*DD, 0,
          nullptr, 0, nullptr,
          ws.w2t, nullptr, nullptr, (long)DD*DD, 0, (long)DD*DD,
          nullptr, 0);
      k_zcalc<<<dim3(NN/4, C), 256, 0, stream>>>(ws.Q, ws.ksum, ws.rs);
      // h += (z * q) @ w2 + attn_outb
      k_mgemm<128,128,false,false,true><<<dim3(64, 2, C), 256, 0, stream>>>(
          ws.Q, PL, 0, 256, 1,
          ws.w2t, 2L*DD*DD, (long)DD*DD,
          ws.rs, NN, attn_outb + (long)i*DD,
          nullptr, nullptr, nullptr, 0, 0, 0, ws.h, PL);
    }

    k_head<<<dim3(NN/4, C), 256, 0, stream>>>(ws.h, head_w, head_b, out + (long)b0*NN*3);
  }
}

// Round 10
// 2653.277 us; speedup vs baseline: 5.2139x; 1.2593x over previous
//
#include <hip/hip_runtime.h>

#define BB 8
#define NN 8192
#define KK 6
#define DD 256
#define LL 5
#define NE (BB*NN*KK)       // 393216
#define PLANE (NN*DD)       // 2097152 elems per batch
#define INV6 (1.0f/6.000001f)

typedef unsigned short u16;
typedef __attribute__((ext_vector_type(8))) _Float16 h8;
typedef __attribute__((ext_vector_type(8))) unsigned short us8;
typedef __attribute__((ext_vector_type(4))) float f32x4;

__device__ __forceinline__ u16 f2h(float f){
  union { _Float16 h; u16 u; } c; c.h = (_Float16)f; return c.u;
}
__device__ __forceinline__ float h2f(u16 u){
  union { _Float16 h; u16 u; } c; c.u = u; return (float)c.h;
}

// async global->LDS 16B copy: LDS dest must be wave-uniform base + lane*16
__device__ __forceinline__ void ldscp(const u16* g, u16* l){
  __builtin_amdgcn_global_load_lds(
      (const __attribute__((address_space(1))) void*)g,
      (__attribute__((address_space(3))) void*)l, 16, 0, 0);
}

// ---------------- CSR build ----------------
__global__ void k_count(const int* __restrict__ knn, int* __restrict__ off){
  int e = blockIdx.x*256 + threadIdx.x;
  if(e >= NE) return;
  int b = e / (NN*KK);
  int j = knn[e];
  atomicAdd(&off[b*(NN+1) + 1 + j], 1);
}

__global__ __launch_bounds__(1024) void k_scan(int* __restrict__ offAll){
  __shared__ int lds[1024];
  __shared__ int carry_s;
  int* off = offAll + blockIdx.x*(NN+1);
  const int len = NN+1;
  int t = threadIdx.x;
  if(t==0) carry_s = 0;
  __syncthreads();
  for(int base=0; base<len; base+=1024){
    int x = (base+t < len) ? off[base+t] : 0;
    lds[t] = x; __syncthreads();
    for(int s=1; s<1024; s<<=1){
      int v = (t>=s) ? lds[t-s] : 0;
      __syncthreads();
      lds[t] += v;
      __syncthreads();
    }
    int incl = lds[t];
    int carry = carry_s;
    __syncthreads();
    if(base+t < len) off[base+t] = incl + carry;
    if(t==1023) carry_s = carry + incl;
    __syncthreads();
  }
}

__global__ void k_fill(const int* __restrict__ knn, int* __restrict__ cursor, int* __restrict__ srcE){
  int e = blockIdx.x*256 + threadIdx.x;
  if(e >= NE) return;
  int b = e / (NN*KK);
  int n = (e % (NN*KK)) / KK;
  int j = knn[e];
  int pos = atomicAdd(&cursor[b*(NN+1) + j], 1);
  srcE[(long)b*NN*KK + pos] = n;
}

// ---- weight prep: W fp32 [L][256][N] -> Wt hi/lo fp16 [L][2][N][256] ----
__global__ __launch_bounds__(256) void k_prepw(const float* __restrict__ W, u16* __restrict__ Wt, int N){
  int n = blockIdx.x, l = blockIdx.y, k = threadIdx.x;
  float x = W[((long)l*256 + k)*N + n];
  u16 hb = f2h(x);
  Wt[(((long)l*2 + 0)*N + n)*256 + k] = hb;
  Wt[(((long)l*2 + 1)*N + n)*256 + k] = f2h(x - h2f(hb));
}

// ---------------- embed ----------------
__global__ __launch_bounds__(256) void k_embed(const float* __restrict__ x, const float* __restrict__ ew,
                        const float* __restrict__ eb, float* __restrict__ h){
  int g = blockIdx.x, z = blockIdx.y, d = threadIdx.x;
  const float* xp = x + ((long)z*NN + g)*3;
  h[(long)z*PLANE + (long)g*DD + d] = xp[0]*ew[0*DD+d] + xp[1]*ew[1*DD+d] + xp[2]*ew[2*DD+d] + eb[d];
}

// ---------------- layernorm fp32 -> fp16 single plane ----------------
__global__ __launch_bounds__(256) void k_ln(const float* __restrict__ h, const float* __restrict__ g,
                     const float* __restrict__ bia, u16* __restrict__ out){
  long z = blockIdx.y;
  int row = blockIdx.x*4 + (threadIdx.x >> 6);
  int lane = threadIdx.x & 63;
  const float4 x = *(const float4*)(h + z*PLANE + (long)row*DD + lane*4);
  float s  = x.x + x.y + x.z + x.w;
  float s2 = x.x*x.x + x.y*x.y + x.z*x.z + x.w*x.w;
  for(int o=1;o<64;o<<=1){ s += __shfl_xor(s,o); s2 += __shfl_xor(s2,o); }
  float m = s*(1.0f/256.0f);
  float var = s2*(1.0f/256.0f) - m*m;
  float r = rsqrtf(var + 1e-5f);
  const float4 gu = *(const float4*)(g + lane*4);
  const float4 bu = *(const float4*)(bia + lane*4);
  ushort4 o4;
  o4.x = f2h((x.x-m)*r*gu.x + bu.x);
  o4.y = f2h((x.y-m)*r*gu.y + bu.y);
  o4.z = f2h((x.z-m)*r*gu.z + bu.z);
  o4.w = f2h((x.w-m)*r*gu.w + bu.w);
  *(ushort4*)(out + z*PLANE + (long)row*DD + lane*4) = o4;
}

// ---------------- fp16 MFMA GEMM ----------------
// C[m][n] = sum_k A[m][k]*B[n][k]. A fp16 staged ldscp (ASPLIT: lo at +aLoOff).
// B fp16 (BSPLIT: hi/lo at +bLoOff) or fp32 on-the-fly (BF32).
// MFMAs: A*Bh [+A*Bl if BSPLIT] [+Al*Bh if ASPLIT].
// kSplit>1 (BM==64 only): K chunked over z, fp32 atomicAdd into accOut.
// BM==128: LDS-roundtrip coalesced epilogue (sections OR accOut+=).
// BM==64: legacy scattered epilogue (supports oLoOff split-pair output).
template<int BM,int BN,bool ASPLIT,bool BF32,bool BSPLIT>
__global__ __launch_bounds__(256) void k_mgemm(
    const u16* __restrict__ A, long aStride, long aLoOff, int K, int kSplit,
    const void* __restrict__ Bv, long bStride, long bLoOff,
    const float* __restrict__ rowscale, long rsStride,
    const float* __restrict__ bias,
    u16* __restrict__ o0, u16* __restrict__ o1, u16* __restrict__ o2,
    long oStride, int reluMask, long oLoOff,
    float* __restrict__ accOut, long hStride)
{
  constexpr int WM = BM/2, WN = BN/2, MT = WM/16, NT = WN/16;
  constexpr int STG = BM*32*(ASPLIT?2:1) + BN*32*(BSPLIT?2:1);
  constexpr int EPI = (BM==128) ? 32*132*2 : 0;
  constexpr int SM  = (STG > EPI) ? STG : EPI;
  __shared__ __align__(16) u16 smem[SM];
  u16* Ahi = smem;
  u16* Alo = smem + BM*32;                       // valid iff ASPLIT
  u16* Bhi = smem + BM*32*(ASPLIT?2:1);
  u16* Blo = Bhi + BN*32;                        // valid iff BSPLIT
  float* epi = (float*)smem;

  const int t = threadIdx.x;
  const int nz = blockIdx.z;
  const long z = nz / kSplit;
  const int chunk = nz % kSplit;
  const int kLen = K / kSplit, kLo = chunk * kLen;
  const int rowTile = blockIdx.x*BM, colTile = blockIdx.y*BN;
  const int l = t & 63, w = t >> 6;
  const int wr = w >> 1, wc = w & 1;
  const int lm = l & 15, kq = l >> 4;

  f32x4 acc[MT][NT];
  #pragma unroll
  for(int mt=0;mt<MT;mt++)
    #pragma unroll
    for(int nt=0;nt<NT;nt++) acc[mt][nt] = (f32x4){0.f,0.f,0.f,0.f};

  for(int k0=kLo; k0<kLo+kLen; k0+=32){
    __syncthreads();
    {
      constexpr int NCH = BM/64;
      #pragma unroll
      for(int li=0; li<NCH; li++){
        int f = li*256 + t;
        int row = f>>2, c = (f&3)*8;
        const u16* gp = A + z*aStride + (long)(rowTile+row)*K + k0 + c;
        ldscp(gp, &Ahi[f*8]);
        if constexpr (ASPLIT) ldscp(gp + aLoOff, &Alo[f*8]);
      }
    }
    if constexpr (BF32){
      constexpr int NCH = BN/64;
      #pragma unroll
      for(int li=0; li<NCH; li++){
        int f = li*256 + t;
        int row = f>>2, c = (f&3)*8;
        const float* src = (const float*)Bv + z*bStride + (long)(colTile+row)*K + k0 + c;
        float4 v0 = ((const float4*)src)[0], v1 = ((const float4*)src)[1];
        us8 hv;
        hv[0]=f2h(v0.x); hv[1]=f2h(v0.y); hv[2]=f2h(v0.z); hv[3]=f2h(v0.w);
        hv[4]=f2h(v1.x); hv[5]=f2h(v1.y); hv[6]=f2h(v1.z); hv[7]=f2h(v1.w);
        *(us8*)&Bhi[f*8] = hv;
      }
    } else {
      constexpr int NCH = BN/64;
      #pragma unroll
      for(int li=0; li<NCH; li++){
        int f = li*256 + t;
        int row = f>>2, c = (f&3)*8;
        const u16* gp = (const u16*)Bv + z*bStride + (long)(colTile+row)*K + k0 + c;
        ldscp(gp, &Bhi[f*8]);
        if constexpr (BSPLIT) ldscp(gp + bLoOff, &Blo[f*8]);
      }
    }
    __syncthreads();
    h8 ah[MT], al[MT], bh[NT], bl[NT];
    #pragma unroll
    for(int mt=0;mt<MT;mt++){
      int idx = (wr*WM + mt*16 + lm)*32 + kq*8;
      ah[mt] = *(const h8*)&Ahi[idx];
      if constexpr (ASPLIT) al[mt] = *(const h8*)&Alo[idx];
    }
    #pragma unroll
    for(int nt=0;nt<NT;nt++){
      int idx = (wc*WN + nt*16 + lm)*32 + kq*8;
      bh[nt] = *(const h8*)&Bhi[idx];
      if constexpr (BSPLIT) bl[nt] = *(const h8*)&Blo[idx];
    }
    #pragma unroll
    for(int mt=0;mt<MT;mt++)
      #pragma unroll
      for(int nt=0;nt<NT;nt++){
        acc[mt][nt] = __builtin_amdgcn_mfma_f32_16x16x32_f16(ah[mt], bh[nt], acc[mt][nt], 0, 0, 0);
        if constexpr (BSPLIT)
          acc[mt][nt] = __builtin_amdgcn_mfma_f32_16x16x32_f16(ah[mt], bl[nt], acc[mt][nt], 0, 0, 0);
        if constexpr (ASPLIT)
          acc[mt][nt] = __builtin_amdgcn_mfma_f32_16x16x32_f16(al[mt], bh[nt], acc[mt][nt], 0, 0, 0);
      }
  }

  // epilogue; C-layout per tile: row = kq*4 + reg, col = lm
  if constexpr (BM == 128){
    const int sec = colTile >> 8;
    u16* osec = (sec==0) ? o0 : ((sec==1) ? o1 : o2);
    const bool relu = (reluMask >> sec) & 1;
    #pragma unroll
    for(int mt=0;mt<MT;mt++){
      __syncthreads();
      // write phase: 32 rows (wr halves) x 128 cols into padded LDS
      #pragma unroll
      for(int r=0;r<4;r++){
        int gm = rowTile + wr*64 + mt*16 + kq*4 + r;
        float sc = rowscale ? rowscale[z*rsStride + gm] : 1.0f;
        int rl = wr*16 + kq*4 + r;
        #pragma unroll
        for(int nt=0;nt<NT;nt++)
          epi[rl*132 + wc*64 + nt*16 + lm] = acc[mt][nt][r]*sc;
      }
      __syncthreads();
      // store phase: 512 segments of 8 cols; 2 per thread, coalesced
      #pragma unroll
      for(int ss=0;ss<2;ss++){
        int s = ss*256 + t;
        int rl = s >> 4, sc8 = (s & 15)*8;
        int gm2 = rowTile + (rl>>4)*64 + mt*16 + (rl & 15);
        float v[8];
        #pragma unroll
        for(int j=0;j<8;j++) v[j] = epi[rl*132 + sc8 + j];
        if(bias){
          const float* bp = bias + colTile + sc8;
          #pragma unroll
          for(int j=0;j<8;j++) v[j] += bp[j];
        }
        if(accOut){
          float* hp = accOut + z*hStride + (long)gm2*256 + colTile + sc8;
          float4 h0 = ((float4*)hp)[0], h1 = ((float4*)hp)[1];
          h0.x += v[0]; h0.y += v[1]; h0.z += v[2]; h0.w += v[3];
          h1.x += v[4]; h1.y += v[5]; h1.z += v[6]; h1.w += v[7];
          ((float4*)hp)[0] = h0; ((float4*)hp)[1] = h1;
        } else {
          us8 o8;
          #pragma unroll
          for(int j=0;j<8;j++){
            float vv = v[j];
            if(relu) vv = fmaxf(vv, 0.f) + 1e-6f;
            o8[j] = f2h(vv);
          }
          *(us8*)(osec + z*oStride + (long)gm2*256 + ((colTile + sc8) & 255)) = o8;
        }
      }
    }
  } else {
    #pragma unroll
    for(int mt=0;mt<MT;mt++){
      #pragma unroll
      for(int r=0;r<4;r++){
        int gm = rowTile + wr*WM + mt*16 + kq*4 + r;
        float sc = rowscale ? rowscale[z*rsStride + gm] : 1.0f;
        if(accOut){
          float* hp = accOut + z*hStride + (long)gm*256;
          if(kSplit > 1){
            #pragma unroll
            for(int nt=0;nt<NT;nt++){
              int gc = colTile + wc*WN + nt*16 + lm;
              atomicAdd(&hp[gc], acc[mt][nt][r]);
            }
          } else {
            #pragma unroll
            for(int nt=0;nt<NT;nt++){
              int gc = colTile + wc*WN + nt*16 + lm;
              hp[gc] += acc[mt][nt][r]*sc + (bias ? bias[gc] : 0.f);
            }
          }
        } else {
          #pragma unroll
          for(int nt=0;nt<NT;nt++){
            int gc = colTile + wc*WN + nt*16 + lm;
            int sec = gc >> 8;
            u16* o = (sec==0) ? o0 : ((sec==1) ? o1 : o2);
            float val = acc[mt][nt][r]*sc + (bias ? bias[gc] : 0.f);
            if((reluMask >> sec) & 1) val = fmaxf(val, 0.f) + 1e-6f;
            if(sec==0 && oLoOff){
              u16* oo = o0 + 2*z*oStride + (long)gm*256 + (gc & 255);
              u16 hb = f2h(val);
              oo[0] = hb;
              oo[oLoOff] = f2h(val - h2f(hb));
            } else {
              o[z*oStride + (long)gm*256 + (gc & 255)] = f2h(val);
            }
          }
        }
      }
    }
  }
}

// ------------- fused k+v spmm gather (fp16 planes, fp32 accum) -------------
// grid = (C, NN/8): batch on blockIdx.x so batch b pins to XCD b (L2 locality).
// MODE 0: write kout,vout fp16. MODE 1: no kout; vout = v3 fp16;
// rs[row] = dot(q, k3) with q fp16.
template<int MODE>
__global__ __launch_bounds__(256) void k_spmm2(
    const u16* __restrict__ kin, const u16* __restrict__ vin,
    const int* __restrict__ offB, const int* __restrict__ srcB,
    u16* __restrict__ kout, u16* __restrict__ vout,
    const u16* __restrict__ q, float* __restrict__ rs){
  long z = blockIdx.x;
  const u16* kp = kin + z*PLANE;
  const u16* vp = vin + z*PLANE;
  const int* off = offB + z*(NN+1);
  const int* sE  = srcB + z*(long)NN*KK;
  int row = blockIdx.y*8 + (threadIdx.x >> 5);
  int l32 = threadIdx.x & 31;
  int d8 = l32*8;
  int s0 = off[row], s1 = off[row+1];
  float ak[8], av[8];
  #pragma unroll
  for(int j=0;j<8;j++){ ak[j]=0.f; av[j]=0.f; }
  int e = s0;
  for(; e+1 < s1; e += 2){
    int n0 = sE[e], n1 = sE[e+1];
    us8 k0 = *(const us8*)(kp + (long)n0*DD + d8);
    us8 k1 = *(const us8*)(kp + (long)n1*DD + d8);
    us8 v0 = *(const us8*)(vp + (long)n0*DD + d8);
    us8 v1 = *(const us8*)(vp + (long)n1*DD + d8);
    #pragma unroll
    for(int j=0;j<8;j++){
      ak[j] += h2f(k0[j]) + h2f(k1[j]);
      av[j] += h2f(v0[j]) + h2f(v1[j]);
    }
  }
  if(e < s1){
    int n0 = sE[e];
    us8 k0 = *(const us8*)(kp + (long)n0*DD + d8);
    us8 v0 = *(const us8*)(vp + (long)n0*DD + d8);
    #pragma unroll
    for(int j=0;j<8;j++){ ak[j] += h2f(k0[j]); av[j] += h2f(v0[j]); }
  }
  if constexpr (MODE == 0){
    us8 ok, ov;
    #pragma unroll
    for(int j=0;j<8;j++){ ok[j] = f2h(ak[j]*INV6); ov[j] = f2h(av[j]*INV6); }
    *(us8*)(kout + z*PLANE + (long)row*DD + d8) = ok;
    *(us8*)(vout + z*PLANE + (long)row*DD + d8) = ov;
  } else {
    us8 ov;
    #pragma unroll
    for(int j=0;j<8;j++) ov[j] = f2h(av[j]*INV6);
    *(us8*)(vout + z*PLANE + (long)row*DD + d8) = ov;
    us8 qv = *(const us8*)(q + z*PLANE + (long)row*DD + d8);
    float s = 0.f;
    #pragma unroll
    for(int j=0;j<8;j++) s += h2f(qv[j]) * ak[j];
    for(int o=1;o<32;o<<=1) s += __shfl_xor(s,o);
    if(l32==0) rs[z*NN + row] = s*INV6;
  }
}

// ---------------- z = 1/(q . ksum + 1e-6), q fp16 ----------------
__global__ __launch_bounds__(256) void k_zcalc(const u16* __restrict__ q, const float* __restrict__ ksum,
                        float* __restrict__ rs){
  long z = blockIdx.y;
  int row = blockIdx.x*4 + (threadIdx.x >> 6);
  int lane = threadIdx.x & 63;
  ushort4 qv = *(const ushort4*)(q + z*PLANE + (long)row*DD + lane*4);
  const float4 c = *(const float4*)(ksum + z*DD + lane*4);
  float s = h2f(qv.x)*c.x + h2f(qv.y)*c.y + h2f(qv.z)*c.z + h2f(qv.w)*c.w;
  for(int o=1;o<64;o<<=1) s += __shfl_xor(s,o);
  if(lane==0) rs[z*NN + row] = 1.0f / (s + 1e-6f);
}

// ---- dual transpose fp16 [8192][256] -> [256][8192]: two tensors per launch ----
__global__ __launch_bounds__(256) void k_transp2(
    const u16* __restrict__ in0, u16* __restrict__ out0,
    const u16* __restrict__ in1, u16* __restrict__ out1){
  __shared__ u16 tile[64][72];
  int zz = blockIdx.z;
  long z = zz >> 1;
  const u16* ip = ((zz & 1) ? in1 : in0) + z*PLANE;
  u16* op = ((zz & 1) ? out1 : out0) + z*PLANE;
  int r0 = blockIdx.x*64, c0 = blockIdx.y*64;
  int t = threadIdx.x;
  {
    int r = t>>2, cg = (t&3)*16;
    *(us8*)&tile[r][cg]   = *(const us8*)(ip + (long)(r0+r)*DD + c0 + cg);
    *(us8*)&tile[r][cg+8] = *(const us8*)(ip + (long)(r0+r)*DD + c0 + cg + 8);
  }
  __syncthreads();
  {
    int c = t>>2, rg = t&3;
    us8 a, b;
    #pragma unroll
    for(int j=0;j<8;j++){ a[j] = tile[rg*16+j][c]; b[j] = tile[rg*16+8+j][c]; }
    u16* dst = op + (long)(c0+c)*NN + r0 + rg*16;
    *(us8*)dst = a; *(us8*)(dst+8) = b;
  }
}

// ---- ksum[d] = sum_n kT[d][n], kT fp16 [256][8192] ----
__global__ __launch_bounds__(256) void k_ksum(const u16* __restrict__ kT, float* __restrict__ ksum){
  long z = blockIdx.y;
  int d = blockIdx.x;
  const u16* p = kT + z*PLANE + (long)d*NN;
  float s = 0.f;
  for(int i=threadIdx.x*8; i<NN; i+=2048){
    us8 a = *(const us8*)(p+i);
    #pragma unroll
    for(int j=0;j<8;j++) s += h2f(a[j]);
  }
  for(int o=1;o<64;o<<=1) s += __shfl_xor(s,o);
  __shared__ float ws4[4];
  int w = threadIdx.x >> 6;
  if((threadIdx.x & 63)==0) ws4[w] = s;
  __syncthreads();
  if(threadIdx.x==0) ksum[z*DD + d] = ws4[0]+ws4[1]+ws4[2]+ws4[3];
}

// ---------------- head ----------------
__global__ __launch_bounds__(256) void k_head(const float* __restrict__ h, const float* __restrict__ hw,
                       const float* __restrict__ hb, float* __restrict__ out){
  long z = blockIdx.y;
  int row = blockIdx.x*4 + (threadIdx.x >> 6);
  int lane = threadIdx.x & 63;
  const float4 x = *(const float4*)(h + z*PLANE + (long)row*DD + lane*4);
  int d0 = lane*4;
  float a0 = x.x*hw[(d0+0)*3+0] + x.y*hw[(d0+1)*3+0] + x.z*hw[(d0+2)*3+0] + x.w*hw[(d0+3)*3+0];
  float a1 = x.x*hw[(d0+0)*3+1] + x.y*hw[(d0+1)*3+1] + x.z*hw[(d0+2)*3+1] + x.w*hw[(d0+3)*3+1];
  float a2 = x.x*hw[(d0+0)*3+2] + x.y*hw[(d0+1)*3+2] + x.z*hw[(d0+2)*3+2] + x.w*hw[(d0+3)*3+2];
  for(int o=1;o<64;o<<=1){
    a0 += __shfl_xor(a0,o); a1 += __shfl_xor(a1,o); a2 += __shfl_xor(a2,o);
  }
  if(lane==0){
    float* op = out + (z*NN + row)*3;
    op[0] = a0 + hb[0];
    op[1] = a1 + hb[1];
    op[2] = a2 + hb[2];
  }
}

struct Carve {
  float *h; u16 *L,*Q,*Bp,*Cp,*T;
  float *kvf; u16 *w2t;
  float *ksum,*rs;
  int *off,*cursor,*srcE;
  u16 *wt_gqkv,*wt_aqkv,*wt_gout,*wt_aout;
  size_t total;
};

static Carve carve(char* base, int C){
  Carve c;
  size_t cur = 0;
  auto bump = [&](size_t bytes)->char*{
    char* p = base ? base + cur : (char*)0;
    cur += (bytes + 255) & ~(size_t)255;
    return p;
  };
  c.h    = (float*)bump((size_t)C*PLANE*4);
  c.L    = (u16*)bump((size_t)C*PLANE*2);   // LN out / kT / k-hop pong
  c.Q    = (u16*)bump((size_t)C*PLANE*2);
  c.Bp   = (u16*)bump((size_t)C*PLANE*2);   // k
  c.Cp   = (u16*)bump((size_t)C*PLANE*2);   // v
  c.T    = (u16*)bump((size_t)C*PLANE*2);   // v-hop pong / v3 / vT
  c.kvf  = (float*)bump((size_t)C*DD*DD*4);
  c.w2t  = (u16*)bump((size_t)C*2*DD*DD*2); // split pair
  c.ksum = (float*)bump((size_t)C*DD*4);
  c.rs   = (float*)bump((size_t)C*NN*4);
  c.off  = (int*)bump((size_t)BB*(NN+1)*4);
  c.cursor=(int*)bump((size_t)BB*(NN+1)*4);
  c.srcE = (int*)bump((size_t)NE*4);
  c.wt_gqkv = (u16*)bump((size_t)LL*2*768*256*2);
  c.wt_aqkv = (u16*)bump((size_t)LL*2*768*256*2);
  c.wt_gout = (u16*)bump((size_t)LL*2*256*256*2);
  c.wt_aout = (u16*)bump((size_t)LL*2*256*256*2);
  c.total = cur;
  return c;
}

extern "C" void kernel_launch(void* const* d_in, const int* in_sizes, int n_in,
                              void* d_out, int out_size, void* d_ws, size_t ws_size,
                              hipStream_t stream)
{
  const float* x        = (const float*)d_in[0];
  const int*   knn      = (const int*)d_in[1];
  const float* emb_w    = (const float*)d_in[2];
  const float* emb_b    = (const float*)d_in[3];
  const float* norm_g   = (const float*)d_in[4];
  const float* norm_b   = (const float*)d_in[5];
  const float* grf_qkv  = (const float*)d_in[6];
  const float* grf_outw = (const float*)d_in[7];
  const float* grf_outb = (const float*)d_in[8];
  const float* attn_qkv = (const float*)d_in[9];
  const float* attn_outw= (const float*)d_in[10];
  const float* attn_outb= (const float*)d_in[11];
  const float* head_w   = (const float*)d_in[12];
  const float* head_b   = (const float*)d_in[13];
  float* out = (float*)d_out;

  int C = 1;
  for(int cc=BB; cc>=1; cc>>=1){ if(carve(nullptr, cc).total <= ws_size){ C = cc; break; } }
  Carve ws = carve((char*)d_ws, C);

  // ---- weight prep (hi/lo fp16, transposed to [N][K]) ----
  k_prepw<<<dim3(768, LL), 256, 0, stream>>>(grf_qkv,  ws.wt_gqkv, 768);
  k_prepw<<<dim3(768, LL), 256, 0, stream>>>(attn_qkv, ws.wt_aqkv, 768);
  k_prepw<<<dim3(256, LL), 256, 0, stream>>>(grf_outw, ws.wt_gout, 256);
  k_prepw<<<dim3(256, LL), 256, 0, stream>>>(attn_outw,ws.wt_aout, 256);

  // ---- CSR build for all batches ----
  hipMemsetAsync(ws.off, 0, (size_t)BB*(NN+1)*sizeof(int), stream);
  k_count<<<dim3((NE+255)/256), 256, 0, stream>>>(knn, ws.off);
  k_scan<<<dim3(BB), 1024, 0, stream>>>(ws.off);
  hipMemcpyAsync(ws.cursor, ws.off, (size_t)BB*(NN+1)*sizeof(int), hipMemcpyDeviceToDevice, stream);
  k_fill<<<dim3((NE+255)/256), 256, 0, stream>>>(knn, ws.cursor, ws.srcE);

  const long PL = PLANE;
  for(int b0=0; b0<BB; b0+=C){
    const int* offB  = ws.off  + (long)b0*(NN+1);
    const int* srcB  = ws.srcE + (long)b0*NN*KK;

    k_embed<<<dim3(NN, C), 256, 0, stream>>>(x + (long)b0*NN*3, emb_w, emb_b, ws.h);

    for(int i=0; i<LL; i++){
      // ===== GRF sublayer =====
      k_ln<<<dim3(NN/4, C), 256, 0, stream>>>(ws.h, norm_g + (2*i)*DD, norm_b + (2*i)*DD, ws.L);
      k_mgemm<128,128,false,false,true><<<dim3(64, 6, C), 256, 0, stream>>>(
          ws.L, PL, 0, 256, 1,
          ws.wt_gqkv + (long)i*2*768*256, 0, (long)768*256,
          nullptr, 0, nullptr,
          ws.Q, ws.Bp, ws.Cp, PL, 0, 0, nullptr, 0);
      // hops: (Bp,Cp)->(L,T)->(Bp,Cp)-> final: v3 into T + fused rowdot
      k_spmm2<0><<<dim3(C, NN/8), 256, 0, stream>>>(ws.Bp, ws.Cp, offB, srcB, ws.L, ws.T, nullptr, nullptr);
      k_spmm2<0><<<dim3(C, NN/8), 256, 0, stream>>>(ws.L,  ws.T,  offB, srcB, ws.Bp, ws.Cp, nullptr, nullptr);
      k_spmm2<1><<<dim3(C, NN/8), 256, 0, stream>>>(ws.Bp, ws.Cp, offB, srcB, nullptr, ws.T, ws.Q, ws.rs);
      // h += (rs * v3) @ grf_outw + grf_outb
      k_mgemm<128,128,false,false,true><<<dim3(64, 2, C), 256, 0, stream>>>(
          ws.T, PL, 0, 256, 1,
          ws.wt_gout + (long)i*2*256*256, 0, (long)256*256,
          ws.rs, NN, grf_outb + (long)i*DD,
          nullptr, nullptr, nullptr, 0, 0, 0, ws.h, PL);

      // ===== linear attention sublayer =====
      k_ln<<<dim3(NN/4, C), 256, 0, stream>>>(ws.h, norm_g + (2*i+1)*DD, norm_b + (2*i+1)*DD, ws.L);
      k_mgemm<128,128,false,false,true><<<dim3(64, 6, C), 256, 0, stream>>>(
          ws.L, PL, 0, 256, 1,
          ws.wt_aqkv + (long)i*2*768*256, 0, (long)768*256,
          nullptr, 0, nullptr,
          ws.Q, ws.Bp, ws.Cp, PL, 3 /* relu+1e-6 on q,k */, 0, nullptr, 0);
      // kT = Bp^T -> L ; vT = Cp^T -> T (one dispatch)
      k_transp2<<<dim3(NN/64, DD/64, 2*C), 256, 0, stream>>>(ws.Bp, ws.L, ws.Cp, ws.T);
      k_ksum<<<dim3(DD, C), 256, 0, stream>>>(ws.L, ws.ksum);
      // kv[d][e] = sum_n kT[d][n] * vT[e][n]  (split-K=8, atomic fp32)
      hipMemsetAsync(ws.kvf, 0, (size_t)C*DD*DD*sizeof(float), stream);
      k_mgemm<64,64,false,false,false><<<dim3(4, 4, C*8), 256, 0, stream>>>(
          ws.L, PL, 0, NN, 8,
          ws.T, PL, 0,
          nullptr, 0, nullptr,
          nullptr, nullptr, nullptr, 0, 0, 0, ws.kvf, (long)DD*DD);
      // w2t[n][d] = sum_e WoutT[n][e](split) * kv[d][e]  -> split fp16 pair
      k_mgemm<64,64,true,true,false><<<dim3(4, 4, C), 256, 0, stream>>>(
          ws.wt_aout + (long)i*2*256*256, 0, (long)256*256, 256, 1,
          ws.kvf, (long)DD*DD, 0,
          nullptr, 0, nullptr,
          ws.w2t, nullptr, nullptr, (long)DD*DD, 0, (long)DD*DD,
          nullptr, 0);
      k_zcalc<<<dim3(NN/4, C), 256, 0, stream>>>(ws.Q, ws.ksum, ws.rs);
      // h += (z * q) @ w2 + attn_outb
      k_mgemm<128,128,false,false,true><<<dim3(64, 2, C), 256, 0, stream>>>(
          ws.Q, PL, 0, 256, 1,
          ws.w2t, 2L*DD*DD, (long)DD*DD,
          ws.rs, NN, attn_outb + (long)i*DD,
          nullptr, nullptr, nullptr, 0, 0, 0, ws.h, PL);
    }

    k_head<<<dim3(NN/4, C), 256, 0, stream>>>(ws.h, head_w, head_b, out + (long)b0*NN*3);
  }
}